// Round 15
// baseline (172.846 us; speedup 1.0000x reference)
//
#include <hip/hip_runtime.h>
#include <hip/hip_bf16.h>
#include <hip/hip_fp16.h>

#define BB 8
#define SS 4096
#define CC 640
#define CDIM 768
#define LTXT 77
#define NTOK 4
#define DH 80
#define ASTR 104   // padded LDS row stride (f16) for attention tiles
#define QTILES 4   // query tiles (64 q each) per attn block

typedef __attribute__((ext_vector_type(8))) _Float16 half8;
typedef __attribute__((ext_vector_type(4))) _Float16 half4;
typedef __attribute__((ext_vector_type(4))) float f32x4;

__device__ inline void gload_lds16(const void* g, void* l) {
    __builtin_amdgcn_global_load_lds((__attribute__((address_space(1))) void*)g,
                                     (__attribute__((address_space(3))) void*)l, 16, 0, 0);
}

// ---------------------------------------------------------------- mega convert
// One launch for all small converts. Job ranges on blockIdx.x:
//   [0,255)      ehs f32 -> ehs16           (255 blocks, 65280 x8 elems)
//   [255,355)    Wq[640][640] -> BqT[n][k]  (10 x 10 tiles)
//   [355,455)    Wo[640][640] -> BoT[n][k]
//   [455,1055)   5 proj weights [768][640] -> WT[640][768] (5 x 120 tiles)
__global__ __launch_bounds__(256)
void mega_convert(const float* __restrict__ ehs, _Float16* __restrict__ ehs16,
                  const float* __restrict__ Wq, _Float16* __restrict__ BqT,
                  const float* __restrict__ Wo, _Float16* __restrict__ BoT,
                  const float* __restrict__ W0, const float* __restrict__ W1,
                  const float* __restrict__ W2, const float* __restrict__ W3,
                  const float* __restrict__ W4,
                  _Float16* __restrict__ T0, _Float16* __restrict__ T1,
                  _Float16* __restrict__ T2, _Float16* __restrict__ T3,
                  _Float16* __restrict__ T4)
{
    __shared__ float t[64][65];
    const int z = blockIdx.x;
    const int tid = threadIdx.x;

    if (z < 255) {                      // ehs convert (no LDS)
        int i = z * 256 + tid;
        const float4* p = (const float4*)(ehs + (size_t)i * 8);
        float4 a = p[0], b = p[1];
        half8 h = {(_Float16)a.x, (_Float16)a.y, (_Float16)a.z, (_Float16)a.w,
                   (_Float16)b.x, (_Float16)b.y, (_Float16)b.z, (_Float16)b.w};
        *(half8*)(ehs16 + (size_t)i * 8) = h;
        return;
    }

    const float* W; _Float16* T; int n0, k0, Kdim;
    if (z < 455) {                      // 640x640 transposes
        int j = z - 255;
        W = (j < 100) ? Wq : Wo;
        T = (j < 100) ? BqT : BoT;
        j %= 100;
        n0 = (j / 10) * 64; k0 = (j % 10) * 64; Kdim = 640;
    } else {                            // 768x640 proj-weight transposes
        int j = z - 455;
        int wsel = j / 120, rem = j % 120;
        W = (wsel == 0) ? W0 : (wsel == 1) ? W1 : (wsel == 2) ? W2 : (wsel == 3) ? W3 : W4;
        T = (wsel == 0) ? T0 : (wsel == 1) ? T1 : (wsel == 2) ? T2 : (wsel == 3) ? T3 : T4;
        n0 = (rem % 10) * 64; k0 = (rem / 10) * 64; Kdim = CDIM;
    }
    for (int idx = tid; idx < 64 * 64; idx += 256) {
        int kk = idx >> 6, nn = idx & 63;
        t[kk][nn] = W[(size_t)(k0 + kk) * 640 + n0 + nn];
    }
    __syncthreads();
    for (int idx = tid; idx < 64 * 64; idx += 256) {
        int nn = idx >> 6, kk = idx & 63;
        T[(size_t)(n0 + nn) * Kdim + k0 + kk] = (_Float16)t[kk][nn];
    }
}

// ---------------------------------------------------------------- proj GEMM + hidden convert (fused launch)
// Blocks [0,230): projection MFMA GEMM. Blocks [230,10470): hidden f32->f16.
__global__ __launch_bounds__(256)
void proj_and_convert(const _Float16* __restrict__ A16,
                      const _Float16* __restrict__ WT0, const _Float16* __restrict__ WT1,
                      const _Float16* __restrict__ WT2, const _Float16* __restrict__ WT3,
                      const _Float16* __restrict__ WT4,
                      _Float16* __restrict__ O0, _Float16* __restrict__ O1,
                      _Float16* __restrict__ O2, _Float16* __restrict__ O3,
                      _Float16* __restrict__ O4,
                      const float* __restrict__ hidden, _Float16* __restrict__ hid16)
{
    __shared__ __align__(16) _Float16 sA[64 * 64];
    __shared__ __align__(16) _Float16 sB[64 * 64];
    const int tid = threadIdx.x;

    if (blockIdx.x >= 230) {            // hidden convert branch
        int i = (blockIdx.x - 230) * 256 + tid;
        if (i < 2621440) {
            const float4* p = (const float4*)(hidden + (size_t)i * 8);
            float4 a = p[0], b = p[1];
            half8 h = {(_Float16)a.x, (_Float16)a.y, (_Float16)a.z, (_Float16)a.w,
                       (_Float16)b.x, (_Float16)b.y, (_Float16)b.z, (_Float16)b.w};
            *(half8*)(hid16 + (size_t)i * 8) = h;
        }
        return;
    }

    const int job = blockIdx.x;
    int wsel, mtile, ntile;
    if (job < 200) { wsel = job / 100; mtile = (job % 100) / 10; ntile = job % 10; }
    else { int j = job - 200; wsel = 2 + j / 10; mtile = 0; ntile = j % 10; }
    const _Float16* WT = (wsel == 0) ? WT0 : (wsel == 1) ? WT1 : (wsel == 2) ? WT2 : (wsel == 3) ? WT3 : WT4;
    const int Mv = (wsel < 2) ? 616 : 32;
    const int bm = mtile * 64, bn = ntile * 64;

    const _Float16* asrc[2];
    const _Float16* bsrc[2];
    int sslot[2];
    #pragma unroll
    for (int p = 0; p < 2; ++p) {
        int s = p * 256 + tid;
        int row = s >> 3, sub = s & 7;
        int c = sub ^ (row & 7);
        int m = bm + row; if (m > Mv - 1) m = Mv - 1;
        int srcrow;
        if (wsel < 2) srcrow = (m / 77) * 85 + (m % 77);
        else { int b2 = m >> 2, t2 = m & 3; srcrow = b2 * 85 + ((wsel == 4) ? 81 : 77) + t2; }
        asrc[p] = A16 + (size_t)srcrow * CDIM + c * 8;
        bsrc[p] = WT + (size_t)(bn + row) * CDIM + c * 8;
        sslot[p] = s * 8;
    }

    const int lane = tid & 63, w = tid >> 6;
    const int wm = w >> 1, wn = w & 1;
    const int lrow = lane & 15, lhi = lane >> 4;

    f32x4 acc[2][2];
    #pragma unroll
    for (int mt = 0; mt < 2; ++mt)
        #pragma unroll
        for (int nt = 0; nt < 2; ++nt)
            acc[mt][nt] = (f32x4){0.f, 0.f, 0.f, 0.f};

    for (int k0 = 0; k0 < CDIM; k0 += 64) {
        #pragma unroll
        for (int p = 0; p < 2; ++p) {
            gload_lds16(asrc[p] + k0, sA + sslot[p]);
            gload_lds16(bsrc[p] + k0, sB + sslot[p]);
        }
        __syncthreads();
        #pragma unroll
        for (int ks = 0; ks < 2; ++ks) {
            half8 af[2], bf[2];
            #pragma unroll
            for (int mt = 0; mt < 2; ++mt) {
                int row = wm * 32 + mt * 16 + lrow;
                int sub = (ks * 4 + lhi) ^ (row & 7);
                af[mt] = *(const half8*)&sA[row * 64 + sub * 8];
            }
            #pragma unroll
            for (int nt = 0; nt < 2; ++nt) {
                int row = wn * 32 + nt * 16 + lrow;
                int sub = (ks * 4 + lhi) ^ (row & 7);
                bf[nt] = *(const half8*)&sB[row * 64 + sub * 8];
            }
            #pragma unroll
            for (int mt = 0; mt < 2; ++mt)
                #pragma unroll
                for (int nt = 0; nt < 2; ++nt)
                    acc[mt][nt] = __builtin_amdgcn_mfma_f32_16x16x32_f16(af[mt], bf[nt], acc[mt][nt], 0, 0, 0);
        }
        __syncthreads();
    }

    _Float16* Op = (wsel == 0) ? O0 : (wsel == 2) ? O2 : O4;
    #pragma unroll
    for (int mt = 0; mt < 2; ++mt) {
        #pragma unroll
        for (int nt = 0; nt < 2; ++nt) {
            int col = bn + wn * 32 + nt * 16 + lrow;
            #pragma unroll
            for (int r = 0; r < 4; ++r) {
                int m = bm + wm * 32 + mt * 16 + lhi * 4 + r;
                if (m < Mv) {
                    _Float16 val = (_Float16)acc[mt][nt][r];
                    if (wsel == 1) {
                        int bb = m / 77, j = m % 77;
                        O1[((size_t)bb * 640 + col) * 80 + j] = val;
                    } else if (wsel == 3) {
                        int bb = m >> 2, t = m & 3;
                        O3[((size_t)bb * 640 + col) * 4 + t] = val;
                    } else {
                        Op[(size_t)m * 640 + col] = val;
                    }
                }
            }
        }
    }
}

// ---------------------------------------------------------------- f16 MFMA GEMM (2-phase dbuf, T3-minimal)
// C[M,640] = A[M,640] @ BT[640,640]^T. 1D grid 1280, XCD-bijective n-inner swizzle.
// Stage tile t+1 FIRST, compute tile t, ONE barrier per tile (stage latency
// hides under compute; round 14: -9 us vs stage->barrier->compute).
// NOTE: no occupancy bound (round 9: (256,5) forced VGPR 48 -> accvgpr spills).
// EPI 0: f16 store. EPI 1: 0.5*(acc+bias)+resid16, f32 store (resid is f16).
template<int EPI>
__global__ __launch_bounds__(256)
void gemm_f16(const _Float16* __restrict__ A, const _Float16* __restrict__ BT,
              const float* __restrict__ bias, const _Float16* __restrict__ resid,
              void* __restrict__ Cp)
{
    __shared__ __align__(16) _Float16 sA[2][128 * 64];
    __shared__ __align__(16) _Float16 sB[2][128 * 64];

    const int tid = threadIdx.x;
    const int lane = tid & 63;
    const int w = tid >> 6, wm = w >> 1, wn = w & 1;
    const int lrow = lane & 15, lhi = lane >> 4;

    const int orig = blockIdx.x;
    const int wgid = (orig & 7) * 160 + (orig >> 3);
    const int bm = (wgid / 5) * 128, bn = (wgid % 5) * 128;

    const _Float16* asrc[4];
    const _Float16* bsrc[4];
    int sslot[4];
    #pragma unroll
    for (int p = 0; p < 4; ++p) {
        int s = p * 256 + tid;
        int row = s >> 3, sub = s & 7;
        int c = sub ^ (row & 7);                // inverse-swizzled source
        asrc[p] = A  + (size_t)(bm + row) * 640 + c * 8;
        bsrc[p] = BT + (size_t)(bn + row) * 640 + c * 8;
        sslot[p] = s * 8;
    }

    f32x4 acc[4][4];
    #pragma unroll
    for (int mt = 0; mt < 4; ++mt)
        #pragma unroll
        for (int nt = 0; nt < 4; ++nt)
            acc[mt][nt] = (f32x4){0.f, 0.f, 0.f, 0.f};

    #pragma unroll
    for (int p = 0; p < 4; ++p) {
        gload_lds16(asrc[p], &sA[0][sslot[p]]);
        gload_lds16(bsrc[p], &sB[0][sslot[p]]);
    }
    __syncthreads();

    for (int t = 0; t < 10; ++t) {
        const int cur = t & 1;
        if (t < 9) {
            const int k1 = (t + 1) * 64;
            #pragma unroll
            for (int p = 0; p < 4; ++p) {
                gload_lds16(asrc[p] + k1, &sA[cur ^ 1][sslot[p]]);
                gload_lds16(bsrc[p] + k1, &sB[cur ^ 1][sslot[p]]);
            }
        }
        __builtin_amdgcn_s_setprio(1);
        #pragma unroll
        for (int ks = 0; ks < 2; ++ks) {
            half8 af[4], bf[4];
            #pragma unroll
            for (int mt = 0; mt < 4; ++mt) {
                int row = wm * 64 + mt * 16 + lrow;
                int sub = (ks * 4 + lhi) ^ (row & 7);
                af[mt] = *(const half8*)&sA[cur][row * 64 + sub * 8];
            }
            #pragma unroll
            for (int nt = 0; nt < 4; ++nt) {
                int row = wn * 64 + nt * 16 + lrow;
                int sub = (ks * 4 + lhi) ^ (row & 7);
                bf[nt] = *(const half8*)&sB[cur][row * 64 + sub * 8];
            }
            #pragma unroll
            for (int mt = 0; mt < 4; ++mt)
                #pragma unroll
                for (int nt = 0; nt < 4; ++nt)
                    acc[mt][nt] = __builtin_amdgcn_mfma_f32_16x16x32_f16(af[mt], bf[nt], acc[mt][nt], 0, 0, 0);
        }
        __builtin_amdgcn_s_setprio(0);
        __syncthreads();
    }

    #pragma unroll
    for (int mt = 0; mt < 4; ++mt) {
        #pragma unroll
        for (int nt = 0; nt < 4; ++nt) {
            int row0 = bm + wm * 64 + mt * 16 + lhi * 4;
            int col = bn + wn * 64 + nt * 16 + lrow;
            #pragma unroll
            for (int r = 0; r < 4; ++r) {
                float v = acc[mt][nt][r];
                if (EPI == 0) {
                    ((_Float16*)Cp)[(size_t)(row0 + r) * 640 + col] = (_Float16)v;
                } else {
                    float o = 0.5f * (v + bias[col]) + (float)resid[(size_t)(row0 + r) * 640 + col];
                    ((float*)Cp)[(size_t)(row0 + r) * 640 + col] = o;
                }
            }
        }
    }
}

// ---------------------------------------------------------------- MFMA attention
// Block: QTILES x 64 queries for one (b,h). 4 waves, 16 q-rows per wave per tile.
// K/V staged ONCE per block; tile loop has no barriers (sP rows wave-private).
// SOFTWARE PIPELINE: tile t+1's Q-frags + mask int4 are loaded right after
// tile t's QK MFMAs — global latency hides under softmax+PV (round-14 counters:
// MfmaUtil 5.9 / VALUBusy 20 / occ 20 -> chain-latency-bound, not BW/compute).
// Safe vs in-place qh/attnout alias: prefetch reads tile t+1 rows, stores write
// tile t rows (disjoint); same-tile q-read -> store ordered by data dependency.
// Softmax without max-subtraction (scores small, f32-safe, identical result).
// K-pack rows: 0..76 text, 77..79 zero, 80..83 ip, 84..87 ips, 88..95 zero.
__global__ __launch_bounds__(256, 3)
void attn_kernel(const _Float16* __restrict__ qh,
                 const _Float16* __restrict__ ktxt, const _Float16* __restrict__ vT,
                 const _Float16* __restrict__ ipk, const _Float16* __restrict__ ipvT,
                 const _Float16* __restrict__ ipsk, const int* __restrict__ mask,
                 _Float16* __restrict__ attnout)
{
    __shared__ __align__(16) _Float16 sK[96 * ASTR];
    __shared__ __align__(16) _Float16 sVT[80 * ASTR];
    __shared__ __align__(16) _Float16 sP[64 * ASTR];

    const int tile0 = blockIdx.x * QTILES;
    const int bh = blockIdx.y;
    const int b = bh >> 3, h = bh & 7;
    const int tid = threadIdx.x;
    const float scale = 0.11180339887498948f;   // 1/sqrt(80)
    const half8 hz = {0, 0, 0, 0, 0, 0, 0, 0};

    for (int idx = tid; idx < 96 * 13; idx += 256) {
        int row = idx / 13, c8 = idx % 13;
        half8 v = hz;
        if (c8 < 10) {
            if (row < 77)                       v = *(const half8*)&ktxt[(size_t)(b * LTXT + row) * 640 + h * DH + c8 * 8];
            else if (row >= 80 && row < 84)     v = *(const half8*)&ipk [(size_t)(b * NTOK + row - 80) * 640 + h * DH + c8 * 8];
            else if (row >= 84 && row < 88)     v = *(const half8*)&ipsk[(size_t)(b * NTOK + row - 84) * 640 + h * DH + c8 * 8];
        }
        *(half8*)&sK[row * ASTR + c8 * 8] = v;
    }
    for (int idx = tid; idx < 80 * 13; idx += 256) {
        int row = idx / 13, c8 = idx % 13;
        size_t g = (size_t)b * 640 + h * DH + row;
        half8 v = hz;
        if (c8 < 10) {
            v = *(const half8*)&vT[g * 80 + c8 * 8];
        } else if (c8 == 10) {
            half4 ip = *(const half4*)&ipvT[g * 4];
            v[0] = ip[0]; v[1] = ip[1]; v[2] = ip[2]; v[3] = ip[3];
        }
        *(half8*)&sVT[row * ASTR + c8 * 8] = v;
    }
    __syncthreads();

    const int lane = tid & 63;
    const int w = tid >> 6;
    const int rb = w * 16;
    const int lrow = lane & 15, lhi = lane >> 4;
    const bool t4ok = (64 + lrow) < 77;
    const size_t qstride = (size_t)64 * 640;

    // pipeline prologue: tile 0 Q-frags + mask
    const _Float16* qptr = qh + (size_t)(b * SS + tile0 * 64 + rb + lrow) * 640 + h * DH + lhi * 8;
    half8 a0 = *(const half8*)(qptr);
    half8 a1 = *(const half8*)(qptr + 32);
    half8 a2 = (lhi < 2) ? *(const half8*)(qptr + 64) : hz;
    int4 mq = *(const int4*)&mask[tile0 * 64 + rb + lhi * 4];

    for (int tt = 0; tt < QTILES; ++tt) {
        const int tile = tile0 + tt;

        f32x4 acc[6];
        #pragma unroll
        for (int nt = 0; nt < 6; ++nt) acc[nt] = (f32x4){0.f, 0.f, 0.f, 0.f};

        __builtin_amdgcn_s_setprio(1);
        #pragma unroll
        for (int nt = 0; nt < 6; ++nt) {
            const _Float16* kb = &sK[(nt * 16 + lrow) * ASTR + lhi * 8];
            acc[nt] = __builtin_amdgcn_mfma_f32_16x16x32_f16(a0, *(const half8*)(kb),      acc[nt], 0, 0, 0);
            acc[nt] = __builtin_amdgcn_mfma_f32_16x16x32_f16(a1, *(const half8*)(kb + 32), acc[nt], 0, 0, 0);
            acc[nt] = __builtin_amdgcn_mfma_f32_16x16x32_f16(a2, *(const half8*)(kb + 64), acc[nt], 0, 0, 0);
        }
        __builtin_amdgcn_s_setprio(0);

        // prefetch next tile's Q + mask — latency hides under softmax + PV
        half8 n0 = hz, n1 = hz, n2 = hz;
        int4 mn = mq;
        if (tt + 1 < QTILES) {
            const _Float16* qn = qptr + (size_t)(tt + 1) * qstride;
            n0 = *(const half8*)(qn);
            n1 = *(const half8*)(qn + 32);
            if (lhi < 2) n2 = *(const half8*)(qn + 64);
            mn = *(const int4*)&mask[(tile + 1) * 64 + rb + lhi * 4];
        }

        #pragma unroll
        for (int nt = 0; nt < 6; ++nt) acc[nt] = acc[nt] * scale;

        #pragma unroll
        for (int r = 0; r < 4; ++r) {
            float e0 = __expf(acc[0][r]), e1 = __expf(acc[1][r]);
            float e2 = __expf(acc[2][r]), e3 = __expf(acc[3][r]);
            float e4 = t4ok ? __expf(acc[4][r]) : 0.f;
            float sm = e0 + e1 + e2 + e3 + e4;
            sm += __shfl_xor(sm, 1); sm += __shfl_xor(sm, 2);
            sm += __shfl_xor(sm, 4); sm += __shfl_xor(sm, 8);
            float inv = 1.f / sm;
            acc[0][r] = e0 * inv; acc[1][r] = e1 * inv; acc[2][r] = e2 * inv;
            acc[3][r] = e3 * inv; acc[4][r] = e4 * inv;

            float e5 = __expf(acc[5][r]);
            float sm5 = e5 + __shfl_xor(e5, 1);
            sm5 += __shfl_xor(sm5, 2);
            float p5 = e5 / sm5;
            float po = __shfl_xor(p5, 4);
            int mv = (r == 0) ? mq.x : (r == 1) ? mq.y : (r == 2) ? mq.z : mq.w;
            float fac = (mv != 0) ? 0.01f : 1.0f;
            float pc = fmaxf(p5, po) * fac;
            acc[5][r] = (lrow < 4) ? pc : 0.f;
        }

        #pragma unroll
        for (int nt = 0; nt < 6; ++nt)
            #pragma unroll
            for (int r = 0; r < 4; ++r)
                sP[(rb + lhi * 4 + r) * ASTR + nt * 16 + lrow] = (_Float16)acc[nt][r];

        f32x4 o[5];
        #pragma unroll
        for (int nt = 0; nt < 5; ++nt) o[nt] = (f32x4){0.f, 0.f, 0.f, 0.f};
        {
            const _Float16* pbase = &sP[(rb + lrow) * ASTR + lhi * 8];
            half8 p0 = *(const half8*)(pbase);
            half8 p1 = *(const half8*)(pbase + 32);
            half8 p2 = *(const half8*)(pbase + 64);
            __builtin_amdgcn_s_setprio(1);
            #pragma unroll
            for (int nt = 0; nt < 5; ++nt) {
                const _Float16* vb = &sVT[(nt * 16 + lrow) * ASTR + lhi * 8];
                o[nt] = __builtin_amdgcn_mfma_f32_16x16x32_f16(p0, *(const half8*)(vb),      o[nt], 0, 0, 0);
                o[nt] = __builtin_amdgcn_mfma_f32_16x16x32_f16(p1, *(const half8*)(vb + 32), o[nt], 0, 0, 0);
                o[nt] = __builtin_amdgcn_mfma_f32_16x16x32_f16(p2, *(const half8*)(vb + 64), o[nt], 0, 0, 0);
            }
            __builtin_amdgcn_s_setprio(0);
        }

        #pragma unroll
        for (int nt = 0; nt < 5; ++nt)
            #pragma unroll
            for (int r = 0; r < 4; ++r)
                attnout[(size_t)(b * SS + tile * 64 + rb + lhi * 4 + r) * 640 + h * DH + nt * 16 + lrow] =
                    (_Float16)o[nt][r];

        a0 = n0; a1 = n1; a2 = n2; mq = mn;
    }
}

// ---------------------------------------------------------------- launch
extern "C" void kernel_launch(void* const* d_in, const int* in_sizes, int n_in,
                              void* d_out, int out_size, void* d_ws, size_t ws_size,
                              hipStream_t stream) {
    const float* hidden = (const float*)d_in[0];
    const float* ehs    = (const float*)d_in[1];
    const int*   mask   = (const int*)d_in[2];
    const float* Wq     = (const float*)d_in[3];
    const float* Wk     = (const float*)d_in[4];
    const float* Wv     = (const float*)d_in[5];
    const float* Wkip   = (const float*)d_in[6];
    const float* Wvip   = (const float*)d_in[7];
    const float* Wksip  = (const float*)d_in[8];
    const float* Wo     = (const float*)d_in[9];
    const float* bo     = (const float*)d_in[10];

    // ws layout (total 87,255,040 B, proven footprint):
    //   region A @ 0: ehs16 (1,044,480) + 5 x WT (983,040 ea) = 5,959,680
    //     dead after proj_and_convert; qhA (first written by gemm0) overlays it.
    //   qhA    0           41,943,040   q -> attn out (in-place)
    //   hid16  41,943,040  41,943,040
    //   BqT    83,886,080     819,200
    //   BoT    84,705,280     819,200
    //   ktxt   85,524,480     788,480
    //   vT     86,312,960     819,200   [b*640+d][80]
    //   ipk    87,132,160      40,960
    //   ipvT   87,173,120      40,960   [b*640+d][4]
    //   ipsk   87,214,080      40,960   -> ends 87,255,040
    char* ws = (char*)d_ws;
    _Float16* qhA    = (_Float16*)(ws);
    _Float16* ehs16  = (_Float16*)(ws);                      // overlaid by qhA later
    _Float16* WkT    = (_Float16*)(ws + 1044480);
    _Float16* WvT    = (_Float16*)(ws + 2027520);
    _Float16* WkipT  = (_Float16*)(ws + 3010560);
    _Float16* WvipT  = (_Float16*)(ws + 3993600);
    _Float16* WksipT = (_Float16*)(ws + 4976640);            // region A ends 5,959,680
    _Float16* hid16  = (_Float16*)(ws + 41943040);
    _Float16* BqT    = (_Float16*)(ws + 83886080);
    _Float16* BoT    = (_Float16*)(ws + 84705280);
    _Float16* ktxt   = (_Float16*)(ws + 85524480);
    _Float16* vT     = (_Float16*)(ws + 86312960);
    _Float16* ipk    = (_Float16*)(ws + 87132160);
    _Float16* ipvT   = (_Float16*)(ws + 87173120);
    _Float16* ipsk   = (_Float16*)(ws + 87214080);

    mega_convert<<<1055, 256, 0, stream>>>(ehs, ehs16, Wq, BqT, Wo, BoT,
                                           Wk, Wv, Wkip, Wvip, Wksip,
                                           WkT, WvT, WkipT, WvipT, WksipT);
    proj_and_convert<<<10470, 256, 0, stream>>>(ehs16, WkT, WvT, WkipT, WvipT, WksipT,
                                                ktxt, vT, ipk, ipvT, ipsk,
                                                hidden, hid16);
    gemm_f16<0><<<1280, 256, 0, stream>>>(hid16, BqT, nullptr, nullptr, qhA);
    attn_kernel<<<dim3(64 / QTILES, 64), 256, 0, stream>>>(qhA, ktxt, vT, ipk, ipvT, ipsk, mask, qhA);
    gemm_f16<1><<<1280, 256, 0, stream>>>(qhA, BoT, bo, hid16, d_out);
}

// Round 16
// 165.793 us; speedup vs baseline: 1.0425x; 1.0425x over previous
//
#include <hip/hip_runtime.h>
#include <hip/hip_bf16.h>
#include <hip/hip_fp16.h>

#define BB 8
#define SS 4096
#define CC 640
#define CDIM 768
#define LTXT 77
#define NTOK 4
#define DH 80
#define ASTR 104   // padded LDS row stride (f16) for attention tiles
#define QTILES 4   // query tiles (64 q each) per attn block

typedef __attribute__((ext_vector_type(8))) _Float16 half8;
typedef __attribute__((ext_vector_type(4))) _Float16 half4;
typedef __attribute__((ext_vector_type(4))) float f32x4;

__device__ inline void gload_lds16(const void* g, void* l) {
    __builtin_amdgcn_global_load_lds((__attribute__((address_space(1))) void*)g,
                                     (__attribute__((address_space(3))) void*)l, 16, 0, 0);
}

// ---------------------------------------------------------------- mega convert
// One launch for all small converts. Job ranges on blockIdx.x:
//   [0,255)      ehs f32 -> ehs16           (255 blocks, 65280 x8 elems)
//   [255,355)    Wq[640][640] -> BqT[n][k]  (10 x 10 tiles)
//   [355,455)    Wo[640][640] -> BoT[n][k]
//   [455,1055)   5 proj weights [768][640] -> WT[640][768] (5 x 120 tiles)
__global__ __launch_bounds__(256)
void mega_convert(const float* __restrict__ ehs, _Float16* __restrict__ ehs16,
                  const float* __restrict__ Wq, _Float16* __restrict__ BqT,
                  const float* __restrict__ Wo, _Float16* __restrict__ BoT,
                  const float* __restrict__ W0, const float* __restrict__ W1,
                  const float* __restrict__ W2, const float* __restrict__ W3,
                  const float* __restrict__ W4,
                  _Float16* __restrict__ T0, _Float16* __restrict__ T1,
                  _Float16* __restrict__ T2, _Float16* __restrict__ T3,
                  _Float16* __restrict__ T4)
{
    __shared__ float t[64][65];
    const int z = blockIdx.x;
    const int tid = threadIdx.x;

    if (z < 255) {                      // ehs convert (no LDS)
        int i = z * 256 + tid;
        const float4* p = (const float4*)(ehs + (size_t)i * 8);
        float4 a = p[0], b = p[1];
        half8 h = {(_Float16)a.x, (_Float16)a.y, (_Float16)a.z, (_Float16)a.w,
                   (_Float16)b.x, (_Float16)b.y, (_Float16)b.z, (_Float16)b.w};
        *(half8*)(ehs16 + (size_t)i * 8) = h;
        return;
    }

    const float* W; _Float16* T; int n0, k0, Kdim;
    if (z < 455) {                      // 640x640 transposes
        int j = z - 255;
        W = (j < 100) ? Wq : Wo;
        T = (j < 100) ? BqT : BoT;
        j %= 100;
        n0 = (j / 10) * 64; k0 = (j % 10) * 64; Kdim = 640;
    } else {                            // 768x640 proj-weight transposes
        int j = z - 455;
        int wsel = j / 120, rem = j % 120;
        W = (wsel == 0) ? W0 : (wsel == 1) ? W1 : (wsel == 2) ? W2 : (wsel == 3) ? W3 : W4;
        T = (wsel == 0) ? T0 : (wsel == 1) ? T1 : (wsel == 2) ? T2 : (wsel == 3) ? T3 : T4;
        n0 = (rem % 10) * 64; k0 = (rem / 10) * 64; Kdim = CDIM;
    }
    for (int idx = tid; idx < 64 * 64; idx += 256) {
        int kk = idx >> 6, nn = idx & 63;
        t[kk][nn] = W[(size_t)(k0 + kk) * 640 + n0 + nn];
    }
    __syncthreads();
    for (int idx = tid; idx < 64 * 64; idx += 256) {
        int nn = idx >> 6, kk = idx & 63;
        T[(size_t)(n0 + nn) * Kdim + k0 + kk] = (_Float16)t[kk][nn];
    }
}

// ---------------------------------------------------------------- proj GEMM + hidden convert (fused launch)
// Blocks [0,230): projection MFMA GEMM. Blocks [230,10470): hidden f32->f16.
__global__ __launch_bounds__(256)
void proj_and_convert(const _Float16* __restrict__ A16,
                      const _Float16* __restrict__ WT0, const _Float16* __restrict__ WT1,
                      const _Float16* __restrict__ WT2, const _Float16* __restrict__ WT3,
                      const _Float16* __restrict__ WT4,
                      _Float16* __restrict__ O0, _Float16* __restrict__ O1,
                      _Float16* __restrict__ O2, _Float16* __restrict__ O3,
                      _Float16* __restrict__ O4,
                      const float* __restrict__ hidden, _Float16* __restrict__ hid16)
{
    __shared__ __align__(16) _Float16 sA[64 * 64];
    __shared__ __align__(16) _Float16 sB[64 * 64];
    const int tid = threadIdx.x;

    if (blockIdx.x >= 230) {            // hidden convert branch
        int i = (blockIdx.x - 230) * 256 + tid;
        if (i < 2621440) {
            const float4* p = (const float4*)(hidden + (size_t)i * 8);
            float4 a = p[0], b = p[1];
            half8 h = {(_Float16)a.x, (_Float16)a.y, (_Float16)a.z, (_Float16)a.w,
                       (_Float16)b.x, (_Float16)b.y, (_Float16)b.z, (_Float16)b.w};
            *(half8*)(hid16 + (size_t)i * 8) = h;
        }
        return;
    }

    const int job = blockIdx.x;
    int wsel, mtile, ntile;
    if (job < 200) { wsel = job / 100; mtile = (job % 100) / 10; ntile = job % 10; }
    else { int j = job - 200; wsel = 2 + j / 10; mtile = 0; ntile = j % 10; }
    const _Float16* WT = (wsel == 0) ? WT0 : (wsel == 1) ? WT1 : (wsel == 2) ? WT2 : (wsel == 3) ? WT3 : WT4;
    const int Mv = (wsel < 2) ? 616 : 32;
    const int bm = mtile * 64, bn = ntile * 64;

    const _Float16* asrc[2];
    const _Float16* bsrc[2];
    int sslot[2];
    #pragma unroll
    for (int p = 0; p < 2; ++p) {
        int s = p * 256 + tid;
        int row = s >> 3, sub = s & 7;
        int c = sub ^ (row & 7);
        int m = bm + row; if (m > Mv - 1) m = Mv - 1;
        int srcrow;
        if (wsel < 2) srcrow = (m / 77) * 85 + (m % 77);
        else { int b2 = m >> 2, t2 = m & 3; srcrow = b2 * 85 + ((wsel == 4) ? 81 : 77) + t2; }
        asrc[p] = A16 + (size_t)srcrow * CDIM + c * 8;
        bsrc[p] = WT + (size_t)(bn + row) * CDIM + c * 8;
        sslot[p] = s * 8;
    }

    const int lane = tid & 63, w = tid >> 6;
    const int wm = w >> 1, wn = w & 1;
    const int lrow = lane & 15, lhi = lane >> 4;

    f32x4 acc[2][2];
    #pragma unroll
    for (int mt = 0; mt < 2; ++mt)
        #pragma unroll
        for (int nt = 0; nt < 2; ++nt)
            acc[mt][nt] = (f32x4){0.f, 0.f, 0.f, 0.f};

    for (int k0 = 0; k0 < CDIM; k0 += 64) {
        #pragma unroll
        for (int p = 0; p < 2; ++p) {
            gload_lds16(asrc[p] + k0, sA + sslot[p]);
            gload_lds16(bsrc[p] + k0, sB + sslot[p]);
        }
        __syncthreads();
        #pragma unroll
        for (int ks = 0; ks < 2; ++ks) {
            half8 af[2], bf[2];
            #pragma unroll
            for (int mt = 0; mt < 2; ++mt) {
                int row = wm * 32 + mt * 16 + lrow;
                int sub = (ks * 4 + lhi) ^ (row & 7);
                af[mt] = *(const half8*)&sA[row * 64 + sub * 8];
            }
            #pragma unroll
            for (int nt = 0; nt < 2; ++nt) {
                int row = wn * 32 + nt * 16 + lrow;
                int sub = (ks * 4 + lhi) ^ (row & 7);
                bf[nt] = *(const half8*)&sB[row * 64 + sub * 8];
            }
            #pragma unroll
            for (int mt = 0; mt < 2; ++mt)
                #pragma unroll
                for (int nt = 0; nt < 2; ++nt)
                    acc[mt][nt] = __builtin_amdgcn_mfma_f32_16x16x32_f16(af[mt], bf[nt], acc[mt][nt], 0, 0, 0);
        }
        __syncthreads();
    }

    _Float16* Op = (wsel == 0) ? O0 : (wsel == 2) ? O2 : O4;
    #pragma unroll
    for (int mt = 0; mt < 2; ++mt) {
        #pragma unroll
        for (int nt = 0; nt < 2; ++nt) {
            int col = bn + wn * 32 + nt * 16 + lrow;
            #pragma unroll
            for (int r = 0; r < 4; ++r) {
                int m = bm + wm * 32 + mt * 16 + lhi * 4 + r;
                if (m < Mv) {
                    _Float16 val = (_Float16)acc[mt][nt][r];
                    if (wsel == 1) {
                        int bb = m / 77, j = m % 77;
                        O1[((size_t)bb * 640 + col) * 80 + j] = val;
                    } else if (wsel == 3) {
                        int bb = m >> 2, t = m & 3;
                        O3[((size_t)bb * 640 + col) * 4 + t] = val;
                    } else {
                        Op[(size_t)m * 640 + col] = val;
                    }
                }
            }
        }
    }
}

// ---------------------------------------------------------------- f16 MFMA GEMM (2-phase dbuf, T3-minimal)
// C[M,640] = A[M,640] @ BT[640,640]^T. 1D grid 1280, XCD-bijective n-inner swizzle.
// Stage tile t+1 FIRST, compute tile t, ONE barrier per tile (stage latency
// hides under compute; round 14: -9 us vs stage->barrier->compute).
// NOTE: no occupancy bound (round 9: (256,5) forced VGPR 48 -> accvgpr spills).
// EPI 0: f16 store. EPI 1: 0.5*(acc+bias)+resid16, f32 store (resid is f16).
template<int EPI>
__global__ __launch_bounds__(256)
void gemm_f16(const _Float16* __restrict__ A, const _Float16* __restrict__ BT,
              const float* __restrict__ bias, const _Float16* __restrict__ resid,
              void* __restrict__ Cp)
{
    __shared__ __align__(16) _Float16 sA[2][128 * 64];
    __shared__ __align__(16) _Float16 sB[2][128 * 64];

    const int tid = threadIdx.x;
    const int lane = tid & 63;
    const int w = tid >> 6, wm = w >> 1, wn = w & 1;
    const int lrow = lane & 15, lhi = lane >> 4;

    const int orig = blockIdx.x;
    const int wgid = (orig & 7) * 160 + (orig >> 3);
    const int bm = (wgid / 5) * 128, bn = (wgid % 5) * 128;

    const _Float16* asrc[4];
    const _Float16* bsrc[4];
    int sslot[4];
    #pragma unroll
    for (int p = 0; p < 4; ++p) {
        int s = p * 256 + tid;
        int row = s >> 3, sub = s & 7;
        int c = sub ^ (row & 7);                // inverse-swizzled source
        asrc[p] = A  + (size_t)(bm + row) * 640 + c * 8;
        bsrc[p] = BT + (size_t)(bn + row) * 640 + c * 8;
        sslot[p] = s * 8;
    }

    f32x4 acc[4][4];
    #pragma unroll
    for (int mt = 0; mt < 4; ++mt)
        #pragma unroll
        for (int nt = 0; nt < 4; ++nt)
            acc[mt][nt] = (f32x4){0.f, 0.f, 0.f, 0.f};

    #pragma unroll
    for (int p = 0; p < 4; ++p) {
        gload_lds16(asrc[p], &sA[0][sslot[p]]);
        gload_lds16(bsrc[p], &sB[0][sslot[p]]);
    }
    __syncthreads();

    for (int t = 0; t < 10; ++t) {
        const int cur = t & 1;
        if (t < 9) {
            const int k1 = (t + 1) * 64;
            #pragma unroll
            for (int p = 0; p < 4; ++p) {
                gload_lds16(asrc[p] + k1, &sA[cur ^ 1][sslot[p]]);
                gload_lds16(bsrc[p] + k1, &sB[cur ^ 1][sslot[p]]);
            }
        }
        __builtin_amdgcn_s_setprio(1);
        #pragma unroll
        for (int ks = 0; ks < 2; ++ks) {
            half8 af[4], bf[4];
            #pragma unroll
            for (int mt = 0; mt < 4; ++mt) {
                int row = wm * 64 + mt * 16 + lrow;
                int sub = (ks * 4 + lhi) ^ (row & 7);
                af[mt] = *(const half8*)&sA[cur][row * 64 + sub * 8];
            }
            #pragma unroll
            for (int nt = 0; nt < 4; ++nt) {
                int row = wn * 64 + nt * 16 + lrow;
                int sub = (ks * 4 + lhi) ^ (row & 7);
                bf[nt] = *(const half8*)&sB[cur][row * 64 + sub * 8];
            }
            #pragma unroll
            for (int mt = 0; mt < 4; ++mt)
                #pragma unroll
                for (int nt = 0; nt < 4; ++nt)
                    acc[mt][nt] = __builtin_amdgcn_mfma_f32_16x16x32_f16(af[mt], bf[nt], acc[mt][nt], 0, 0, 0);
        }
        __builtin_amdgcn_s_setprio(0);
        __syncthreads();
    }

    #pragma unroll
    for (int mt = 0; mt < 4; ++mt) {
        #pragma unroll
        for (int nt = 0; nt < 4; ++nt) {
            int row0 = bm + wm * 64 + mt * 16 + lhi * 4;
            int col = bn + wn * 64 + nt * 16 + lrow;
            #pragma unroll
            for (int r = 0; r < 4; ++r) {
                float v = acc[mt][nt][r];
                if (EPI == 0) {
                    ((_Float16*)Cp)[(size_t)(row0 + r) * 640 + col] = (_Float16)v;
                } else {
                    float o = 0.5f * (v + bias[col]) + (float)resid[(size_t)(row0 + r) * 640 + col];
                    ((float*)Cp)[(size_t)(row0 + r) * 640 + col] = o;
                }
            }
        }
    }
}

// ---------------------------------------------------------------- MFMA attention
// Block: QTILES x 64 queries for one (b,h). 4 waves, 16 q-rows per wave per tile.
// K/V staged ONCE per block; tile loop has no barriers (sP rows wave-private).
// Round-14 structure (Q loaded at loop top — NO cross-tile register prefetch:
// round 15 showed it spills to scratch, doubling FETCH 36->75 MB, +13 us).
// Kept from r15 bundle: mask as one int4 at loop top (off the dependent softmax
// chain) and s_setprio(1) around MFMA clusters (m191: +4-7% on attn).
// Softmax without max-subtraction (scores small, f32-safe, identical result).
// K-pack rows: 0..76 text, 77..79 zero, 80..83 ip, 84..87 ips, 88..95 zero.
// attnout aliases qh (in-place): each wave reads exactly the q it overwrites.
__global__ __launch_bounds__(256, 3)
void attn_kernel(const _Float16* __restrict__ qh,
                 const _Float16* __restrict__ ktxt, const _Float16* __restrict__ vT,
                 const _Float16* __restrict__ ipk, const _Float16* __restrict__ ipvT,
                 const _Float16* __restrict__ ipsk, const int* __restrict__ mask,
                 _Float16* __restrict__ attnout)
{
    __shared__ __align__(16) _Float16 sK[96 * ASTR];
    __shared__ __align__(16) _Float16 sVT[80 * ASTR];
    __shared__ __align__(16) _Float16 sP[64 * ASTR];

    const int tile0 = blockIdx.x * QTILES;
    const int bh = blockIdx.y;
    const int b = bh >> 3, h = bh & 7;
    const int tid = threadIdx.x;
    const float scale = 0.11180339887498948f;   // 1/sqrt(80)
    const half8 hz = {0, 0, 0, 0, 0, 0, 0, 0};

    for (int idx = tid; idx < 96 * 13; idx += 256) {
        int row = idx / 13, c8 = idx % 13;
        half8 v = hz;
        if (c8 < 10) {
            if (row < 77)                       v = *(const half8*)&ktxt[(size_t)(b * LTXT + row) * 640 + h * DH + c8 * 8];
            else if (row >= 80 && row < 84)     v = *(const half8*)&ipk [(size_t)(b * NTOK + row - 80) * 640 + h * DH + c8 * 8];
            else if (row >= 84 && row < 88)     v = *(const half8*)&ipsk[(size_t)(b * NTOK + row - 84) * 640 + h * DH + c8 * 8];
        }
        *(half8*)&sK[row * ASTR + c8 * 8] = v;
    }
    for (int idx = tid; idx < 80 * 13; idx += 256) {
        int row = idx / 13, c8 = idx % 13;
        size_t g = (size_t)b * 640 + h * DH + row;
        half8 v = hz;
        if (c8 < 10) {
            v = *(const half8*)&vT[g * 80 + c8 * 8];
        } else if (c8 == 10) {
            half4 ip = *(const half4*)&ipvT[g * 4];
            v[0] = ip[0]; v[1] = ip[1]; v[2] = ip[2]; v[3] = ip[3];
        }
        *(half8*)&sVT[row * ASTR + c8 * 8] = v;
    }
    __syncthreads();

    const int lane = tid & 63;
    const int w = tid >> 6;
    const int rb = w * 16;
    const int lrow = lane & 15, lhi = lane >> 4;
    const bool t4ok = (64 + lrow) < 77;

    for (int tt = 0; tt < QTILES; ++tt) {
        const int tile = tile0 + tt;

        const _Float16* qbase = qh + (size_t)(b * SS + tile * 64 + rb + lrow) * 640 + h * DH + lhi * 8;
        half8 a0 = *(const half8*)(qbase);
        half8 a1 = *(const half8*)(qbase + 32);
        half8 a2 = (lhi < 2) ? *(const half8*)(qbase + 64) : hz;
        int4 mq = *(const int4*)&mask[tile * 64 + rb + lhi * 4];

        f32x4 acc[6];
        #pragma unroll
        for (int nt = 0; nt < 6; ++nt) acc[nt] = (f32x4){0.f, 0.f, 0.f, 0.f};

        __builtin_amdgcn_s_setprio(1);
        #pragma unroll
        for (int nt = 0; nt < 6; ++nt) {
            const _Float16* kb = &sK[(nt * 16 + lrow) * ASTR + lhi * 8];
            acc[nt] = __builtin_amdgcn_mfma_f32_16x16x32_f16(a0, *(const half8*)(kb),      acc[nt], 0, 0, 0);
            acc[nt] = __builtin_amdgcn_mfma_f32_16x16x32_f16(a1, *(const half8*)(kb + 32), acc[nt], 0, 0, 0);
            acc[nt] = __builtin_amdgcn_mfma_f32_16x16x32_f16(a2, *(const half8*)(kb + 64), acc[nt], 0, 0, 0);
        }
        __builtin_amdgcn_s_setprio(0);

        #pragma unroll
        for (int nt = 0; nt < 6; ++nt) acc[nt] = acc[nt] * scale;

        #pragma unroll
        for (int r = 0; r < 4; ++r) {
            float e0 = __expf(acc[0][r]), e1 = __expf(acc[1][r]);
            float e2 = __expf(acc[2][r]), e3 = __expf(acc[3][r]);
            float e4 = t4ok ? __expf(acc[4][r]) : 0.f;
            float sm = e0 + e1 + e2 + e3 + e4;
            sm += __shfl_xor(sm, 1); sm += __shfl_xor(sm, 2);
            sm += __shfl_xor(sm, 4); sm += __shfl_xor(sm, 8);
            float inv = 1.f / sm;
            acc[0][r] = e0 * inv; acc[1][r] = e1 * inv; acc[2][r] = e2 * inv;
            acc[3][r] = e3 * inv; acc[4][r] = e4 * inv;

            float e5 = __expf(acc[5][r]);
            float sm5 = e5 + __shfl_xor(e5, 1);
            sm5 += __shfl_xor(sm5, 2);
            float p5 = e5 / sm5;
            float po = __shfl_xor(p5, 4);
            int mv = (r == 0) ? mq.x : (r == 1) ? mq.y : (r == 2) ? mq.z : mq.w;
            float fac = (mv != 0) ? 0.01f : 1.0f;
            float pc = fmaxf(p5, po) * fac;
            acc[5][r] = (lrow < 4) ? pc : 0.f;
        }

        #pragma unroll
        for (int nt = 0; nt < 6; ++nt)
            #pragma unroll
            for (int r = 0; r < 4; ++r)
                sP[(rb + lhi * 4 + r) * ASTR + nt * 16 + lrow] = (_Float16)acc[nt][r];

        f32x4 o[5];
        #pragma unroll
        for (int nt = 0; nt < 5; ++nt) o[nt] = (f32x4){0.f, 0.f, 0.f, 0.f};
        {
            const _Float16* pbase = &sP[(rb + lrow) * ASTR + lhi * 8];
            half8 p0 = *(const half8*)(pbase);
            half8 p1 = *(const half8*)(pbase + 32);
            half8 p2 = *(const half8*)(pbase + 64);
            __builtin_amdgcn_s_setprio(1);
            #pragma unroll
            for (int nt = 0; nt < 5; ++nt) {
                const _Float16* vb = &sVT[(nt * 16 + lrow) * ASTR + lhi * 8];
                o[nt] = __builtin_amdgcn_mfma_f32_16x16x32_f16(p0, *(const half8*)(vb),      o[nt], 0, 0, 0);
                o[nt] = __builtin_amdgcn_mfma_f32_16x16x32_f16(p1, *(const half8*)(vb + 32), o[nt], 0, 0, 0);
                o[nt] = __builtin_amdgcn_mfma_f32_16x16x32_f16(p2, *(const half8*)(vb + 64), o[nt], 0, 0, 0);
            }
            __builtin_amdgcn_s_setprio(0);
        }

        #pragma unroll
        for (int nt = 0; nt < 5; ++nt)
            #pragma unroll
            for (int r = 0; r < 4; ++r)
                attnout[(size_t)(b * SS + tile * 64 + rb + lhi * 4 + r) * 640 + h * DH + nt * 16 + lrow] =
                    (_Float16)o[nt][r];
    }
}

// ---------------------------------------------------------------- launch
extern "C" void kernel_launch(void* const* d_in, const int* in_sizes, int n_in,
                              void* d_out, int out_size, void* d_ws, size_t ws_size,
                              hipStream_t stream) {
    const float* hidden = (const float*)d_in[0];
    const float* ehs    = (const float*)d_in[1];
    const int*   mask   = (const int*)d_in[2];
    const float* Wq     = (const float*)d_in[3];
    const float* Wk     = (const float*)d_in[4];
    const float* Wv     = (const float*)d_in[5];
    const float* Wkip   = (const float*)d_in[6];
    const float* Wvip   = (const float*)d_in[7];
    const float* Wksip  = (const float*)d_in[8];
    const float* Wo     = (const float*)d_in[9];
    const float* bo     = (const float*)d_in[10];

    // ws layout (total 87,255,040 B, proven footprint):
    //   region A @ 0: ehs16 (1,044,480) + 5 x WT (983,040 ea) = 5,959,680
    //     dead after proj_and_convert; qhA (first written by gemm0) overlays it.
    //   qhA    0           41,943,040   q -> attn out (in-place)
    //   hid16  41,943,040  41,943,040
    //   BqT    83,886,080     819,200
    //   BoT    84,705,280     819,200
    //   ktxt   85,524,480     788,480
    //   vT     86,312,960     819,200   [b*640+d][80]
    //   ipk    87,132,160      40,960
    //   ipvT   87,173,120      40,960   [b*640+d][4]
    //   ipsk   87,214,080      40,960   -> ends 87,255,040
    char* ws = (char*)d_ws;
    _Float16* qhA    = (_Float16*)(ws);
    _Float16* ehs16  = (_Float16*)(ws);                      // overlaid by qhA later
    _Float16* WkT    = (_Float16*)(ws + 1044480);
    _Float16* WvT    = (_Float16*)(ws + 2027520);
    _Float16* WkipT  = (_Float16*)(ws + 3010560);
    _Float16* WvipT  = (_Float16*)(ws + 3993600);
    _Float16* WksipT = (_Float16*)(ws + 4976640);            // region A ends 5,959,680
    _Float16* hid16  = (_Float16*)(ws + 41943040);
    _Float16* BqT    = (_Float16*)(ws + 83886080);
    _Float16* BoT    = (_Float16*)(ws + 84705280);
    _Float16* ktxt   = (_Float16*)(ws + 85524480);
    _Float16* vT     = (_Float16*)(ws + 86312960);
    _Float16* ipk    = (_Float16*)(ws + 87132160);
    _Float16* ipvT   = (_Float16*)(ws + 87173120);
    _Float16* ipsk   = (_Float16*)(ws + 87214080);

    mega_convert<<<1055, 256, 0, stream>>>(ehs, ehs16, Wq, BqT, Wo, BoT,
                                           Wk, Wv, Wkip, Wvip, Wksip,
                                           WkT, WvT, WkipT, WvipT, WksipT);
    proj_and_convert<<<10470, 256, 0, stream>>>(ehs16, WkT, WvT, WkipT, WvipT, WksipT,
                                                ktxt, vT, ipk, ipvT, ipsk,
                                                hidden, hid16);
    gemm_f16<0><<<1280, 256, 0, stream>>>(hid16, BqT, nullptr, nullptr, qhA);
    attn_kernel<<<dim3(64 / QTILES, 64), 256, 0, stream>>>(qhA, ktxt, vT, ipk, ipvT, ipsk, mask, qhA);
    gemm_f16<1><<<1280, 256, 0, stream>>>(qhA, BoT, bo, hid16, d_out);
}

// Round 17
// 162.971 us; speedup vs baseline: 1.0606x; 1.0173x over previous
//
#include <hip/hip_runtime.h>
#include <hip/hip_bf16.h>
#include <hip/hip_fp16.h>

#define BB 8
#define SS 4096
#define CC 640
#define CDIM 768
#define LTXT 77
#define NTOK 4
#define DH 80
#define ASTR 104   // padded LDS row stride (f16) for attention tiles
#define QTILES 4   // query tiles (64 q each) per attn block

typedef __attribute__((ext_vector_type(8))) _Float16 half8;
typedef __attribute__((ext_vector_type(4))) _Float16 half4;
typedef __attribute__((ext_vector_type(4))) float f32x4;

__device__ inline void gload_lds16(const void* g, void* l) {
    __builtin_amdgcn_global_load_lds((__attribute__((address_space(1))) void*)g,
                                     (__attribute__((address_space(3))) void*)l, 16, 0, 0);
}

// ---------------------------------------------------------------- mega convert
// One launch for all small converts. Job ranges on blockIdx.x:
//   [0,255)      ehs f32 -> ehs16           (255 blocks, 65280 x8 elems)
//   [255,355)    Wq[640][640] -> BqT[n][k]  (10 x 10 tiles)
//   [355,455)    Wo[640][640] -> BoT[n][k]
//   [455,1055)   5 proj weights [768][640] -> WT[640][768] (5 x 120 tiles)
__global__ __launch_bounds__(256)
void mega_convert(const float* __restrict__ ehs, _Float16* __restrict__ ehs16,
                  const float* __restrict__ Wq, _Float16* __restrict__ BqT,
                  const float* __restrict__ Wo, _Float16* __restrict__ BoT,
                  const float* __restrict__ W0, const float* __restrict__ W1,
                  const float* __restrict__ W2, const float* __restrict__ W3,
                  const float* __restrict__ W4,
                  _Float16* __restrict__ T0, _Float16* __restrict__ T1,
                  _Float16* __restrict__ T2, _Float16* __restrict__ T3,
                  _Float16* __restrict__ T4)
{
    __shared__ float t[64][65];
    const int z = blockIdx.x;
    const int tid = threadIdx.x;

    if (z < 255) {                      // ehs convert (no LDS)
        int i = z * 256 + tid;
        const float4* p = (const float4*)(ehs + (size_t)i * 8);
        float4 a = p[0], b = p[1];
        half8 h = {(_Float16)a.x, (_Float16)a.y, (_Float16)a.z, (_Float16)a.w,
                   (_Float16)b.x, (_Float16)b.y, (_Float16)b.z, (_Float16)b.w};
        *(half8*)(ehs16 + (size_t)i * 8) = h;
        return;
    }

    const float* W; _Float16* T; int n0, k0, Kdim;
    if (z < 455) {                      // 640x640 transposes
        int j = z - 255;
        W = (j < 100) ? Wq : Wo;
        T = (j < 100) ? BqT : BoT;
        j %= 100;
        n0 = (j / 10) * 64; k0 = (j % 10) * 64; Kdim = 640;
    } else {                            // 768x640 proj-weight transposes
        int j = z - 455;
        int wsel = j / 120, rem = j % 120;
        W = (wsel == 0) ? W0 : (wsel == 1) ? W1 : (wsel == 2) ? W2 : (wsel == 3) ? W3 : W4;
        T = (wsel == 0) ? T0 : (wsel == 1) ? T1 : (wsel == 2) ? T2 : (wsel == 3) ? T3 : T4;
        n0 = (rem % 10) * 64; k0 = (rem / 10) * 64; Kdim = CDIM;
    }
    for (int idx = tid; idx < 64 * 64; idx += 256) {
        int kk = idx >> 6, nn = idx & 63;
        t[kk][nn] = W[(size_t)(k0 + kk) * 640 + n0 + nn];
    }
    __syncthreads();
    for (int idx = tid; idx < 64 * 64; idx += 256) {
        int nn = idx >> 6, kk = idx & 63;
        T[(size_t)(n0 + nn) * Kdim + k0 + kk] = (_Float16)t[kk][nn];
    }
}

// ---------------------------------------------------------------- proj GEMM + hidden convert (fused launch)
// Blocks [0,230): projection MFMA GEMM. Blocks [230,10470): hidden f32->f16.
__global__ __launch_bounds__(256)
void proj_and_convert(const _Float16* __restrict__ A16,
                      const _Float16* __restrict__ WT0, const _Float16* __restrict__ WT1,
                      const _Float16* __restrict__ WT2, const _Float16* __restrict__ WT3,
                      const _Float16* __restrict__ WT4,
                      _Float16* __restrict__ O0, _Float16* __restrict__ O1,
                      _Float16* __restrict__ O2, _Float16* __restrict__ O3,
                      _Float16* __restrict__ O4,
                      const float* __restrict__ hidden, _Float16* __restrict__ hid16)
{
    __shared__ __align__(16) _Float16 sA[64 * 64];
    __shared__ __align__(16) _Float16 sB[64 * 64];
    const int tid = threadIdx.x;

    if (blockIdx.x >= 230) {            // hidden convert branch
        int i = (blockIdx.x - 230) * 256 + tid;
        if (i < 2621440) {
            const float4* p = (const float4*)(hidden + (size_t)i * 8);
            float4 a = p[0], b = p[1];
            half8 h = {(_Float16)a.x, (_Float16)a.y, (_Float16)a.z, (_Float16)a.w,
                       (_Float16)b.x, (_Float16)b.y, (_Float16)b.z, (_Float16)b.w};
            *(half8*)(hid16 + (size_t)i * 8) = h;
        }
        return;
    }

    const int job = blockIdx.x;
    int wsel, mtile, ntile;
    if (job < 200) { wsel = job / 100; mtile = (job % 100) / 10; ntile = job % 10; }
    else { int j = job - 200; wsel = 2 + j / 10; mtile = 0; ntile = j % 10; }
    const _Float16* WT = (wsel == 0) ? WT0 : (wsel == 1) ? WT1 : (wsel == 2) ? WT2 : (wsel == 3) ? WT3 : WT4;
    const int Mv = (wsel < 2) ? 616 : 32;
    const int bm = mtile * 64, bn = ntile * 64;

    const _Float16* asrc[2];
    const _Float16* bsrc[2];
    int sslot[2];
    #pragma unroll
    for (int p = 0; p < 2; ++p) {
        int s = p * 256 + tid;
        int row = s >> 3, sub = s & 7;
        int c = sub ^ (row & 7);
        int m = bm + row; if (m > Mv - 1) m = Mv - 1;
        int srcrow;
        if (wsel < 2) srcrow = (m / 77) * 85 + (m % 77);
        else { int b2 = m >> 2, t2 = m & 3; srcrow = b2 * 85 + ((wsel == 4) ? 81 : 77) + t2; }
        asrc[p] = A16 + (size_t)srcrow * CDIM + c * 8;
        bsrc[p] = WT + (size_t)(bn + row) * CDIM + c * 8;
        sslot[p] = s * 8;
    }

    const int lane = tid & 63, w = tid >> 6;
    const int wm = w >> 1, wn = w & 1;
    const int lrow = lane & 15, lhi = lane >> 4;

    f32x4 acc[2][2];
    #pragma unroll
    for (int mt = 0; mt < 2; ++mt)
        #pragma unroll
        for (int nt = 0; nt < 2; ++nt)
            acc[mt][nt] = (f32x4){0.f, 0.f, 0.f, 0.f};

    for (int k0 = 0; k0 < CDIM; k0 += 64) {
        #pragma unroll
        for (int p = 0; p < 2; ++p) {
            gload_lds16(asrc[p] + k0, sA + sslot[p]);
            gload_lds16(bsrc[p] + k0, sB + sslot[p]);
        }
        __syncthreads();
        #pragma unroll
        for (int ks = 0; ks < 2; ++ks) {
            half8 af[2], bf[2];
            #pragma unroll
            for (int mt = 0; mt < 2; ++mt) {
                int row = wm * 32 + mt * 16 + lrow;
                int sub = (ks * 4 + lhi) ^ (row & 7);
                af[mt] = *(const half8*)&sA[row * 64 + sub * 8];
            }
            #pragma unroll
            for (int nt = 0; nt < 2; ++nt) {
                int row = wn * 32 + nt * 16 + lrow;
                int sub = (ks * 4 + lhi) ^ (row & 7);
                bf[nt] = *(const half8*)&sB[row * 64 + sub * 8];
            }
            #pragma unroll
            for (int mt = 0; mt < 2; ++mt)
                #pragma unroll
                for (int nt = 0; nt < 2; ++nt)
                    acc[mt][nt] = __builtin_amdgcn_mfma_f32_16x16x32_f16(af[mt], bf[nt], acc[mt][nt], 0, 0, 0);
        }
        __syncthreads();
    }

    _Float16* Op = (wsel == 0) ? O0 : (wsel == 2) ? O2 : O4;
    #pragma unroll
    for (int mt = 0; mt < 2; ++mt) {
        #pragma unroll
        for (int nt = 0; nt < 2; ++nt) {
            int col = bn + wn * 32 + nt * 16 + lrow;
            #pragma unroll
            for (int r = 0; r < 4; ++r) {
                int m = bm + wm * 32 + mt * 16 + lhi * 4 + r;
                if (m < Mv) {
                    _Float16 val = (_Float16)acc[mt][nt][r];
                    if (wsel == 1) {
                        int bb = m / 77, j = m % 77;
                        O1[((size_t)bb * 640 + col) * 80 + j] = val;
                    } else if (wsel == 3) {
                        int bb = m >> 2, t = m & 3;
                        O3[((size_t)bb * 640 + col) * 4 + t] = val;
                    } else {
                        Op[(size_t)m * 640 + col] = val;
                    }
                }
            }
        }
    }
}

// ---------------------------------------------------------------- f16 MFMA GEMM (2-phase dbuf, T3-minimal)
// C[M,640] = A[M,640] @ BT[640,640]^T. 1D grid 1280, XCD-bijective n-inner swizzle.
// Stage tile t+1 FIRST, compute tile t, ONE barrier per tile (stage latency
// hides under compute; round 14: -9 us vs stage->barrier->compute).
// NOTE: no occupancy bound (round 9: (256,5) forced VGPR 48 -> accvgpr spills).
// EPI 0: f16 store. EPI 1: 0.5*(acc+bias)+resid16, f32 store (resid is f16).
template<int EPI>
__global__ __launch_bounds__(256)
void gemm_f16(const _Float16* __restrict__ A, const _Float16* __restrict__ BT,
              const float* __restrict__ bias, const _Float16* __restrict__ resid,
              void* __restrict__ Cp)
{
    __shared__ __align__(16) _Float16 sA[2][128 * 64];
    __shared__ __align__(16) _Float16 sB[2][128 * 64];

    const int tid = threadIdx.x;
    const int lane = tid & 63;
    const int w = tid >> 6, wm = w >> 1, wn = w & 1;
    const int lrow = lane & 15, lhi = lane >> 4;

    const int orig = blockIdx.x;
    const int wgid = (orig & 7) * 160 + (orig >> 3);
    const int bm = (wgid / 5) * 128, bn = (wgid % 5) * 128;

    const _Float16* asrc[4];
    const _Float16* bsrc[4];
    int sslot[4];
    #pragma unroll
    for (int p = 0; p < 4; ++p) {
        int s = p * 256 + tid;
        int row = s >> 3, sub = s & 7;
        int c = sub ^ (row & 7);                // inverse-swizzled source
        asrc[p] = A  + (size_t)(bm + row) * 640 + c * 8;
        bsrc[p] = BT + (size_t)(bn + row) * 640 + c * 8;
        sslot[p] = s * 8;
    }

    f32x4 acc[4][4];
    #pragma unroll
    for (int mt = 0; mt < 4; ++mt)
        #pragma unroll
        for (int nt = 0; nt < 4; ++nt)
            acc[mt][nt] = (f32x4){0.f, 0.f, 0.f, 0.f};

    #pragma unroll
    for (int p = 0; p < 4; ++p) {
        gload_lds16(asrc[p], &sA[0][sslot[p]]);
        gload_lds16(bsrc[p], &sB[0][sslot[p]]);
    }
    __syncthreads();

    for (int t = 0; t < 10; ++t) {
        const int cur = t & 1;
        if (t < 9) {
            const int k1 = (t + 1) * 64;
            #pragma unroll
            for (int p = 0; p < 4; ++p) {
                gload_lds16(asrc[p] + k1, &sA[cur ^ 1][sslot[p]]);
                gload_lds16(bsrc[p] + k1, &sB[cur ^ 1][sslot[p]]);
            }
        }
        __builtin_amdgcn_s_setprio(1);
        #pragma unroll
        for (int ks = 0; ks < 2; ++ks) {
            half8 af[4], bf[4];
            #pragma unroll
            for (int mt = 0; mt < 4; ++mt) {
                int row = wm * 64 + mt * 16 + lrow;
                int sub = (ks * 4 + lhi) ^ (row & 7);
                af[mt] = *(const half8*)&sA[cur][row * 64 + sub * 8];
            }
            #pragma unroll
            for (int nt = 0; nt < 4; ++nt) {
                int row = wn * 64 + nt * 16 + lrow;
                int sub = (ks * 4 + lhi) ^ (row & 7);
                bf[nt] = *(const half8*)&sB[cur][row * 64 + sub * 8];
            }
            #pragma unroll
            for (int mt = 0; mt < 4; ++mt)
                #pragma unroll
                for (int nt = 0; nt < 4; ++nt)
                    acc[mt][nt] = __builtin_amdgcn_mfma_f32_16x16x32_f16(af[mt], bf[nt], acc[mt][nt], 0, 0, 0);
        }
        __builtin_amdgcn_s_setprio(0);
        __syncthreads();
    }

    #pragma unroll
    for (int mt = 0; mt < 4; ++mt) {
        #pragma unroll
        for (int nt = 0; nt < 4; ++nt) {
            int row0 = bm + wm * 64 + mt * 16 + lhi * 4;
            int col = bn + wn * 64 + nt * 16 + lrow;
            #pragma unroll
            for (int r = 0; r < 4; ++r) {
                float v = acc[mt][nt][r];
                if (EPI == 0) {
                    ((_Float16*)Cp)[(size_t)(row0 + r) * 640 + col] = (_Float16)v;
                } else {
                    float o = 0.5f * (v + bias[col]) + (float)resid[(size_t)(row0 + r) * 640 + col];
                    ((float*)Cp)[(size_t)(row0 + r) * 640 + col] = o;
                }
            }
        }
    }
}

// ---------------------------------------------------------------- MFMA attention
// EXACT round-14 body (best measured: 53.0-55.1 us, FETCH 36.3 MB). Round-15's
// cross-tile Q prefetch spilled to scratch (FETCH 36->75 MB, +13 us); round-16's
// int4-mask + setprio variant also nudged spills (FETCH +7.5 MB, +3 us). Q and
// scalar mask load at loop top is the right depth for this 84-VGPR budget.
// Block: QTILES x 64 queries for one (b,h). 4 waves, 16 q-rows per wave per tile.
// K/V staged ONCE per block; tile loop has no barriers (sP rows wave-private).
// Softmax without max-subtraction (scores small, f32-safe, identical result).
// K-pack rows: 0..76 text, 77..79 zero, 80..83 ip, 84..87 ips, 88..95 zero.
// attnout aliases qh (in-place): each wave reads exactly the q it overwrites.
__global__ __launch_bounds__(256, 3)
void attn_kernel(const _Float16* __restrict__ qh,
                 const _Float16* __restrict__ ktxt, const _Float16* __restrict__ vT,
                 const _Float16* __restrict__ ipk, const _Float16* __restrict__ ipvT,
                 const _Float16* __restrict__ ipsk, const int* __restrict__ mask,
                 _Float16* __restrict__ attnout)
{
    __shared__ __align__(16) _Float16 sK[96 * ASTR];
    __shared__ __align__(16) _Float16 sVT[80 * ASTR];
    __shared__ __align__(16) _Float16 sP[64 * ASTR];

    const int tile0 = blockIdx.x * QTILES;
    const int bh = blockIdx.y;
    const int b = bh >> 3, h = bh & 7;
    const int tid = threadIdx.x;
    const float scale = 0.11180339887498948f;   // 1/sqrt(80)
    const half8 hz = {0, 0, 0, 0, 0, 0, 0, 0};

    for (int idx = tid; idx < 96 * 13; idx += 256) {
        int row = idx / 13, c8 = idx % 13;
        half8 v = hz;
        if (c8 < 10) {
            if (row < 77)                       v = *(const half8*)&ktxt[(size_t)(b * LTXT + row) * 640 + h * DH + c8 * 8];
            else if (row >= 80 && row < 84)     v = *(const half8*)&ipk [(size_t)(b * NTOK + row - 80) * 640 + h * DH + c8 * 8];
            else if (row >= 84 && row < 88)     v = *(const half8*)&ipsk[(size_t)(b * NTOK + row - 84) * 640 + h * DH + c8 * 8];
        }
        *(half8*)&sK[row * ASTR + c8 * 8] = v;
    }
    for (int idx = tid; idx < 80 * 13; idx += 256) {
        int row = idx / 13, c8 = idx % 13;
        size_t g = (size_t)b * 640 + h * DH + row;
        half8 v = hz;
        if (c8 < 10) {
            v = *(const half8*)&vT[g * 80 + c8 * 8];
        } else if (c8 == 10) {
            half4 ip = *(const half4*)&ipvT[g * 4];
            v[0] = ip[0]; v[1] = ip[1]; v[2] = ip[2]; v[3] = ip[3];
        }
        *(half8*)&sVT[row * ASTR + c8 * 8] = v;
    }
    __syncthreads();

    const int lane = tid & 63;
    const int w = tid >> 6;
    const int rb = w * 16;
    const int lrow = lane & 15, lhi = lane >> 4;
    const bool t4ok = (64 + lrow) < 77;

    for (int tt = 0; tt < QTILES; ++tt) {
        const int tile = tile0 + tt;

        const _Float16* qbase = qh + (size_t)(b * SS + tile * 64 + rb + lrow) * 640 + h * DH + lhi * 8;
        half8 a0 = *(const half8*)(qbase);
        half8 a1 = *(const half8*)(qbase + 32);
        half8 a2 = (lhi < 2) ? *(const half8*)(qbase + 64) : hz;

        f32x4 acc[6];
        #pragma unroll
        for (int nt = 0; nt < 6; ++nt) acc[nt] = (f32x4){0.f, 0.f, 0.f, 0.f};

        #pragma unroll
        for (int nt = 0; nt < 6; ++nt) {
            const _Float16* kb = &sK[(nt * 16 + lrow) * ASTR + lhi * 8];
            acc[nt] = __builtin_amdgcn_mfma_f32_16x16x32_f16(a0, *(const half8*)(kb),      acc[nt], 0, 0, 0);
            acc[nt] = __builtin_amdgcn_mfma_f32_16x16x32_f16(a1, *(const half8*)(kb + 32), acc[nt], 0, 0, 0);
            acc[nt] = __builtin_amdgcn_mfma_f32_16x16x32_f16(a2, *(const half8*)(kb + 64), acc[nt], 0, 0, 0);
        }

        #pragma unroll
        for (int nt = 0; nt < 6; ++nt) acc[nt] = acc[nt] * scale;

        #pragma unroll
        for (int r = 0; r < 4; ++r) {
            float e0 = __expf(acc[0][r]), e1 = __expf(acc[1][r]);
            float e2 = __expf(acc[2][r]), e3 = __expf(acc[3][r]);
            float e4 = t4ok ? __expf(acc[4][r]) : 0.f;
            float sm = e0 + e1 + e2 + e3 + e4;
            sm += __shfl_xor(sm, 1); sm += __shfl_xor(sm, 2);
            sm += __shfl_xor(sm, 4); sm += __shfl_xor(sm, 8);
            float inv = 1.f / sm;
            acc[0][r] = e0 * inv; acc[1][r] = e1 * inv; acc[2][r] = e2 * inv;
            acc[3][r] = e3 * inv; acc[4][r] = e4 * inv;

            float e5 = __expf(acc[5][r]);
            float sm5 = e5 + __shfl_xor(e5, 1);
            sm5 += __shfl_xor(sm5, 2);
            float p5 = e5 / sm5;
            float po = __shfl_xor(p5, 4);
            int gq = tile * 64 + rb + lhi * 4 + r;
            float fac = (mask[gq] != 0) ? 0.01f : 1.0f;
            float pc = fmaxf(p5, po) * fac;
            acc[5][r] = (lrow < 4) ? pc : 0.f;
        }

        #pragma unroll
        for (int nt = 0; nt < 6; ++nt)
            #pragma unroll
            for (int r = 0; r < 4; ++r)
                sP[(rb + lhi * 4 + r) * ASTR + nt * 16 + lrow] = (_Float16)acc[nt][r];

        f32x4 o[5];
        #pragma unroll
        for (int nt = 0; nt < 5; ++nt) o[nt] = (f32x4){0.f, 0.f, 0.f, 0.f};
        {
            const _Float16* pbase = &sP[(rb + lrow) * ASTR + lhi * 8];
            half8 p0 = *(const half8*)(pbase);
            half8 p1 = *(const half8*)(pbase + 32);
            half8 p2 = *(const half8*)(pbase + 64);
            #pragma unroll
            for (int nt = 0; nt < 5; ++nt) {
                const _Float16* vb = &sVT[(nt * 16 + lrow) * ASTR + lhi * 8];
                o[nt] = __builtin_amdgcn_mfma_f32_16x16x32_f16(p0, *(const half8*)(vb),      o[nt], 0, 0, 0);
                o[nt] = __builtin_amdgcn_mfma_f32_16x16x32_f16(p1, *(const half8*)(vb + 32), o[nt], 0, 0, 0);
                o[nt] = __builtin_amdgcn_mfma_f32_16x16x32_f16(p2, *(const half8*)(vb + 64), o[nt], 0, 0, 0);
            }
        }

        #pragma unroll
        for (int nt = 0; nt < 5; ++nt)
            #pragma unroll
            for (int r = 0; r < 4; ++r)
                attnout[(size_t)(b * SS + tile * 64 + rb + lhi * 4 + r) * 640 + h * DH + nt * 16 + lrow] =
                    (_Float16)o[nt][r];
    }
}

// ---------------------------------------------------------------- launch
extern "C" void kernel_launch(void* const* d_in, const int* in_sizes, int n_in,
                              void* d_out, int out_size, void* d_ws, size_t ws_size,
                              hipStream_t stream) {
    const float* hidden = (const float*)d_in[0];
    const float* ehs    = (const float*)d_in[1];
    const int*   mask   = (const int*)d_in[2];
    const float* Wq     = (const float*)d_in[3];
    const float* Wk     = (const float*)d_in[4];
    const float* Wv     = (const float*)d_in[5];
    const float* Wkip   = (const float*)d_in[6];
    const float* Wvip   = (const float*)d_in[7];
    const float* Wksip  = (const float*)d_in[8];
    const float* Wo     = (const float*)d_in[9];
    const float* bo     = (const float*)d_in[10];

    // ws layout (total 87,255,040 B, proven footprint):
    //   region A @ 0: ehs16 (1,044,480) + 5 x WT (983,040 ea) = 5,959,680
    //     dead after proj_and_convert; qhA (first written by gemm0) overlays it.
    //   qhA    0           41,943,040   q -> attn out (in-place)
    //   hid16  41,943,040  41,943,040
    //   BqT    83,886,080     819,200
    //   BoT    84,705,280     819,200
    //   ktxt   85,524,480     788,480
    //   vT     86,312,960     819,200   [b*640+d][80]
    //   ipk    87,132,160      40,960
    //   ipvT   87,173,120      40,960   [b*640+d][4]
    //   ipsk   87,214,080      40,960   -> ends 87,255,040
    char* ws = (char*)d_ws;
    _Float16* qhA    = (_Float16*)(ws);
    _Float16* ehs16  = (_Float16*)(ws);                      // overlaid by qhA later
    _Float16* WkT    = (_Float16*)(ws + 1044480);
    _Float16* WvT    = (_Float16*)(ws + 2027520);
    _Float16* WkipT  = (_Float16*)(ws + 3010560);
    _Float16* WvipT  = (_Float16*)(ws + 3993600);
    _Float16* WksipT = (_Float16*)(ws + 4976640);            // region A ends 5,959,680
    _Float16* hid16  = (_Float16*)(ws + 41943040);
    _Float16* BqT    = (_Float16*)(ws + 83886080);
    _Float16* BoT    = (_Float16*)(ws + 84705280);
    _Float16* ktxt   = (_Float16*)(ws + 85524480);
    _Float16* vT     = (_Float16*)(ws + 86312960);
    _Float16* ipk    = (_Float16*)(ws + 87132160);
    _Float16* ipvT   = (_Float16*)(ws + 87173120);
    _Float16* ipsk   = (_Float16*)(ws + 87214080);

    mega_convert<<<1055, 256, 0, stream>>>(ehs, ehs16, Wq, BqT, Wo, BoT,
                                           Wk, Wv, Wkip, Wvip, Wksip,
                                           WkT, WvT, WkipT, WvipT, WksipT);
    proj_and_convert<<<10470, 256, 0, stream>>>(ehs16, WkT, WvT, WkipT, WvipT, WksipT,
                                                ktxt, vT, ipk, ipvT, ipsk,
                                                hidden, hid16);
    gemm_f16<0><<<1280, 256, 0, stream>>>(hid16, BqT, nullptr, nullptr, qhA);
    attn_kernel<<<dim3(64 / QTILES, 64), 256, 0, stream>>>(qhA, ktxt, vT, ipk, ipvT, ipsk, mask, qhA);
    gemm_f16<1><<<1280, 256, 0, stream>>>(qhA, BoT, bo, hid16, d_out);
}

// Round 18
// 154.474 us; speedup vs baseline: 1.1189x; 1.0550x over previous
//
#include <hip/hip_runtime.h>
#include <hip/hip_bf16.h>
#include <hip/hip_fp16.h>

#define BB 8
#define SS 4096
#define CC 640
#define CDIM 768
#define LTXT 77
#define NTOK 4
#define DH 80
#define ASTR 104   // padded LDS row stride (f16) for attention tiles

typedef __attribute__((ext_vector_type(8))) _Float16 half8;
typedef __attribute__((ext_vector_type(4))) _Float16 half4;
typedef __attribute__((ext_vector_type(4))) float f32x4;

__device__ inline void gload_lds16(const void* g, void* l) {
    __builtin_amdgcn_global_load_lds((__attribute__((address_space(1))) void*)g,
                                     (__attribute__((address_space(3))) void*)l, 16, 0, 0);
}

// ---------------------------------------------------------------- mega convert
// One launch for all small converts. Job ranges on blockIdx.x:
//   [0,255)      ehs f32 -> ehs16           (255 blocks, 65280 x8 elems)
//   [255,355)    Wq[640][640] -> BqT[n][k]  (10 x 10 tiles)
//   [355,455)    Wo[640][640] -> BoT[n][k]
//   [455,1055)   5 proj weights [768][640] -> WT[640][768] (5 x 120 tiles)
__global__ __launch_bounds__(256)
void mega_convert(const float* __restrict__ ehs, _Float16* __restrict__ ehs16,
                  const float* __restrict__ Wq, _Float16* __restrict__ BqT,
                  const float* __restrict__ Wo, _Float16* __restrict__ BoT,
                  const float* __restrict__ W0, const float* __restrict__ W1,
                  const float* __restrict__ W2, const float* __restrict__ W3,
                  const float* __restrict__ W4,
                  _Float16* __restrict__ T0, _Float16* __restrict__ T1,
                  _Float16* __restrict__ T2, _Float16* __restrict__ T3,
                  _Float16* __restrict__ T4)
{
    __shared__ float t[64][65];
    const int z = blockIdx.x;
    const int tid = threadIdx.x;

    if (z < 255) {                      // ehs convert (no LDS)
        int i = z * 256 + tid;
        const float4* p = (const float4*)(ehs + (size_t)i * 8);
        float4 a = p[0], b = p[1];
        half8 h = {(_Float16)a.x, (_Float16)a.y, (_Float16)a.z, (_Float16)a.w,
                   (_Float16)b.x, (_Float16)b.y, (_Float16)b.z, (_Float16)b.w};
        *(half8*)(ehs16 + (size_t)i * 8) = h;
        return;
    }

    const float* W; _Float16* T; int n0, k0, Kdim;
    if (z < 455) {                      // 640x640 transposes
        int j = z - 255;
        W = (j < 100) ? Wq : Wo;
        T = (j < 100) ? BqT : BoT;
        j %= 100;
        n0 = (j / 10) * 64; k0 = (j % 10) * 64; Kdim = 640;
    } else {                            // 768x640 proj-weight transposes
        int j = z - 455;
        int wsel = j / 120, rem = j % 120;
        W = (wsel == 0) ? W0 : (wsel == 1) ? W1 : (wsel == 2) ? W2 : (wsel == 3) ? W3 : W4;
        T = (wsel == 0) ? T0 : (wsel == 1) ? T1 : (wsel == 2) ? T2 : (wsel == 3) ? T3 : T4;
        n0 = (rem % 10) * 64; k0 = (rem / 10) * 64; Kdim = CDIM;
    }
    for (int idx = tid; idx < 64 * 64; idx += 256) {
        int kk = idx >> 6, nn = idx & 63;
        t[kk][nn] = W[(size_t)(k0 + kk) * 640 + n0 + nn];
    }
    __syncthreads();
    for (int idx = tid; idx < 64 * 64; idx += 256) {
        int nn = idx >> 6, kk = idx & 63;
        T[(size_t)(n0 + nn) * Kdim + k0 + kk] = (_Float16)t[kk][nn];
    }
}

// ---------------------------------------------------------------- proj GEMM + hidden convert (fused launch)
// Blocks [0,230): projection MFMA GEMM. Blocks [230,10470): hidden f32->f16.
__global__ __launch_bounds__(256)
void proj_and_convert(const _Float16* __restrict__ A16,
                      const _Float16* __restrict__ WT0, const _Float16* __restrict__ WT1,
                      const _Float16* __restrict__ WT2, const _Float16* __restrict__ WT3,
                      const _Float16* __restrict__ WT4,
                      _Float16* __restrict__ O0, _Float16* __restrict__ O1,
                      _Float16* __restrict__ O2, _Float16* __restrict__ O3,
                      _Float16* __restrict__ O4,
                      const float* __restrict__ hidden, _Float16* __restrict__ hid16)
{
    __shared__ __align__(16) _Float16 sA[64 * 64];
    __shared__ __align__(16) _Float16 sB[64 * 64];
    const int tid = threadIdx.x;

    if (blockIdx.x >= 230) {            // hidden convert branch
        int i = (blockIdx.x - 230) * 256 + tid;
        if (i < 2621440) {
            const float4* p = (const float4*)(hidden + (size_t)i * 8);
            float4 a = p[0], b = p[1];
            half8 h = {(_Float16)a.x, (_Float16)a.y, (_Float16)a.z, (_Float16)a.w,
                       (_Float16)b.x, (_Float16)b.y, (_Float16)b.z, (_Float16)b.w};
            *(half8*)(hid16 + (size_t)i * 8) = h;
        }
        return;
    }

    const int job = blockIdx.x;
    int wsel, mtile, ntile;
    if (job < 200) { wsel = job / 100; mtile = (job % 100) / 10; ntile = job % 10; }
    else { int j = job - 200; wsel = 2 + j / 10; mtile = 0; ntile = j % 10; }
    const _Float16* WT = (wsel == 0) ? WT0 : (wsel == 1) ? WT1 : (wsel == 2) ? WT2 : (wsel == 3) ? WT3 : WT4;
    const int Mv = (wsel < 2) ? 616 : 32;
    const int bm = mtile * 64, bn = ntile * 64;

    const _Float16* asrc[2];
    const _Float16* bsrc[2];
    int sslot[2];
    #pragma unroll
    for (int p = 0; p < 2; ++p) {
        int s = p * 256 + tid;
        int row = s >> 3, sub = s & 7;
        int c = sub ^ (row & 7);
        int m = bm + row; if (m > Mv - 1) m = Mv - 1;
        int srcrow;
        if (wsel < 2) srcrow = (m / 77) * 85 + (m % 77);
        else { int b2 = m >> 2, t2 = m & 3; srcrow = b2 * 85 + ((wsel == 4) ? 81 : 77) + t2; }
        asrc[p] = A16 + (size_t)srcrow * CDIM + c * 8;
        bsrc[p] = WT + (size_t)(bn + row) * CDIM + c * 8;
        sslot[p] = s * 8;
    }

    const int lane = tid & 63, w = tid >> 6;
    const int wm = w >> 1, wn = w & 1;
    const int lrow = lane & 15, lhi = lane >> 4;

    f32x4 acc[2][2];
    #pragma unroll
    for (int mt = 0; mt < 2; ++mt)
        #pragma unroll
        for (int nt = 0; nt < 2; ++nt)
            acc[mt][nt] = (f32x4){0.f, 0.f, 0.f, 0.f};

    for (int k0 = 0; k0 < CDIM; k0 += 64) {
        #pragma unroll
        for (int p = 0; p < 2; ++p) {
            gload_lds16(asrc[p] + k0, sA + sslot[p]);
            gload_lds16(bsrc[p] + k0, sB + sslot[p]);
        }
        __syncthreads();
        #pragma unroll
        for (int ks = 0; ks < 2; ++ks) {
            half8 af[2], bf[2];
            #pragma unroll
            for (int mt = 0; mt < 2; ++mt) {
                int row = wm * 32 + mt * 16 + lrow;
                int sub = (ks * 4 + lhi) ^ (row & 7);
                af[mt] = *(const half8*)&sA[row * 64 + sub * 8];
            }
            #pragma unroll
            for (int nt = 0; nt < 2; ++nt) {
                int row = wn * 32 + nt * 16 + lrow;
                int sub = (ks * 4 + lhi) ^ (row & 7);
                bf[nt] = *(const half8*)&sB[row * 64 + sub * 8];
            }
            #pragma unroll
            for (int mt = 0; mt < 2; ++mt)
                #pragma unroll
                for (int nt = 0; nt < 2; ++nt)
                    acc[mt][nt] = __builtin_amdgcn_mfma_f32_16x16x32_f16(af[mt], bf[nt], acc[mt][nt], 0, 0, 0);
        }
        __syncthreads();
    }

    _Float16* Op = (wsel == 0) ? O0 : (wsel == 2) ? O2 : O4;
    #pragma unroll
    for (int mt = 0; mt < 2; ++mt) {
        #pragma unroll
        for (int nt = 0; nt < 2; ++nt) {
            int col = bn + wn * 32 + nt * 16 + lrow;
            #pragma unroll
            for (int r = 0; r < 4; ++r) {
                int m = bm + wm * 32 + mt * 16 + lhi * 4 + r;
                if (m < Mv) {
                    _Float16 val = (_Float16)acc[mt][nt][r];
                    if (wsel == 1) {
                        int bb = m / 77, j = m % 77;
                        O1[((size_t)bb * 640 + col) * 80 + j] = val;
                    } else if (wsel == 3) {
                        int bb = m >> 2, t = m & 3;
                        O3[((size_t)bb * 640 + col) * 4 + t] = val;
                    } else {
                        Op[(size_t)m * 640 + col] = val;
                    }
                }
            }
        }
    }
}

// ---------------------------------------------------------------- f16 MFMA GEMM (2-phase dbuf, T3-minimal)
// C[M,640] = A[M,640] @ BT[640,640]^T. 1D grid 1280, XCD-bijective n-inner swizzle.
// Stage tile t+1 FIRST, compute tile t, ONE barrier per tile (stage latency
// hides under compute; round 14: -9 us vs stage->barrier->compute).
// NOTE: no occupancy bound (round 9: (256,5) forced VGPR 48 -> accvgpr spills).
// EPI 0: f16 store. EPI 1: 0.5*(acc+bias)+resid16, f32 store (resid is f16).
template<int EPI>
__global__ __launch_bounds__(256)
void gemm_f16(const _Float16* __restrict__ A, const _Float16* __restrict__ BT,
              const float* __restrict__ bias, const _Float16* __restrict__ resid,
              void* __restrict__ Cp)
{
    __shared__ __align__(16) _Float16 sA[2][128 * 64];
    __shared__ __align__(16) _Float16 sB[2][128 * 64];

    const int tid = threadIdx.x;
    const int lane = tid & 63;
    const int w = tid >> 6, wm = w >> 1, wn = w & 1;
    const int lrow = lane & 15, lhi = lane >> 4;

    const int orig = blockIdx.x;
    const int wgid = (orig & 7) * 160 + (orig >> 3);
    const int bm = (wgid / 5) * 128, bn = (wgid % 5) * 128;

    const _Float16* asrc[4];
    const _Float16* bsrc[4];
    int sslot[4];
    #pragma unroll
    for (int p = 0; p < 4; ++p) {
        int s = p * 256 + tid;
        int row = s >> 3, sub = s & 7;
        int c = sub ^ (row & 7);                // inverse-swizzled source
        asrc[p] = A  + (size_t)(bm + row) * 640 + c * 8;
        bsrc[p] = BT + (size_t)(bn + row) * 640 + c * 8;
        sslot[p] = s * 8;
    }

    f32x4 acc[4][4];
    #pragma unroll
    for (int mt = 0; mt < 4; ++mt)
        #pragma unroll
        for (int nt = 0; nt < 4; ++nt)
            acc[mt][nt] = (f32x4){0.f, 0.f, 0.f, 0.f};

    #pragma unroll
    for (int p = 0; p < 4; ++p) {
        gload_lds16(asrc[p], &sA[0][sslot[p]]);
        gload_lds16(bsrc[p], &sB[0][sslot[p]]);
    }
    __syncthreads();

    for (int t = 0; t < 10; ++t) {
        const int cur = t & 1;
        if (t < 9) {
            const int k1 = (t + 1) * 64;
            #pragma unroll
            for (int p = 0; p < 4; ++p) {
                gload_lds16(asrc[p] + k1, &sA[cur ^ 1][sslot[p]]);
                gload_lds16(bsrc[p] + k1, &sB[cur ^ 1][sslot[p]]);
            }
        }
        __builtin_amdgcn_s_setprio(1);
        #pragma unroll
        for (int ks = 0; ks < 2; ++ks) {
            half8 af[4], bf[4];
            #pragma unroll
            for (int mt = 0; mt < 4; ++mt) {
                int row = wm * 64 + mt * 16 + lrow;
                int sub = (ks * 4 + lhi) ^ (row & 7);
                af[mt] = *(const half8*)&sA[cur][row * 64 + sub * 8];
            }
            #pragma unroll
            for (int nt = 0; nt < 4; ++nt) {
                int row = wn * 64 + nt * 16 + lrow;
                int sub = (ks * 4 + lhi) ^ (row & 7);
                bf[nt] = *(const half8*)&sB[cur][row * 64 + sub * 8];
            }
            #pragma unroll
            for (int mt = 0; mt < 4; ++mt)
                #pragma unroll
                for (int nt = 0; nt < 4; ++nt)
                    acc[mt][nt] = __builtin_amdgcn_mfma_f32_16x16x32_f16(af[mt], bf[nt], acc[mt][nt], 0, 0, 0);
        }
        __builtin_amdgcn_s_setprio(0);
        __syncthreads();
    }

    #pragma unroll
    for (int mt = 0; mt < 4; ++mt) {
        #pragma unroll
        for (int nt = 0; nt < 4; ++nt) {
            int row0 = bm + wm * 64 + mt * 16 + lhi * 4;
            int col = bn + wn * 64 + nt * 16 + lrow;
            #pragma unroll
            for (int r = 0; r < 4; ++r) {
                float v = acc[mt][nt][r];
                if (EPI == 0) {
                    ((_Float16*)Cp)[(size_t)(row0 + r) * 640 + col] = (_Float16)v;
                } else {
                    float o = 0.5f * (v + bias[col]) + (float)resid[(size_t)(row0 + r) * 640 + col];
                    ((float*)Cp)[(size_t)(row0 + r) * 640 + col] = o;
                }
            }
        }
    }
}

// ---------------------------------------------------------------- MFMA attention (8-wave blocks)
// Per-wave code is byte-identical to the round-14/17 optimum (best measured);
// ONLY the wave count per block changes: 512 threads = 8 waves, each owning 16
// q-rows of a 128-row iteration, 2 iterations = 256 q per block. K/V staged
// once per 256 q (same amortization as before); sP widened to 128 rows.
// LDS 63.2 KB -> 2 blocks/CU x 8 waves = 16 waves/CU vs 12 before (+33% TLP on
// a 70%-stall latency-bound kernel; r17 counters: MfmaUtil 5.8, VALUBusy 20).
// VGPR unchanged (~84) -> 6 waves/SIMD supported, no spill risk.
// Softmax without max-subtraction (scores small, f32-safe, identical result).
// K-pack rows: 0..76 text, 77..79 zero, 80..83 ip, 84..87 ips, 88..95 zero.
// attnout aliases qh (in-place): each wave reads exactly the q it overwrites.
__global__ __launch_bounds__(512)
void attn_kernel(const _Float16* __restrict__ qh,
                 const _Float16* __restrict__ ktxt, const _Float16* __restrict__ vT,
                 const _Float16* __restrict__ ipk, const _Float16* __restrict__ ipvT,
                 const _Float16* __restrict__ ipsk, const int* __restrict__ mask,
                 _Float16* __restrict__ attnout)
{
    __shared__ __align__(16) _Float16 sK[96 * ASTR];
    __shared__ __align__(16) _Float16 sVT[80 * ASTR];
    __shared__ __align__(16) _Float16 sP[128 * ASTR];

    const int q0 = blockIdx.x * 256;            // 256 q-rows per block
    const int bh = blockIdx.y;
    const int b = bh >> 3, h = bh & 7;
    const int tid = threadIdx.x;
    const float scale = 0.11180339887498948f;   // 1/sqrt(80)
    const half8 hz = {0, 0, 0, 0, 0, 0, 0, 0};

    for (int idx = tid; idx < 96 * 13; idx += 512) {
        int row = idx / 13, c8 = idx % 13;
        half8 v = hz;
        if (c8 < 10) {
            if (row < 77)                       v = *(const half8*)&ktxt[(size_t)(b * LTXT + row) * 640 + h * DH + c8 * 8];
            else if (row >= 80 && row < 84)     v = *(const half8*)&ipk [(size_t)(b * NTOK + row - 80) * 640 + h * DH + c8 * 8];
            else if (row >= 84 && row < 88)     v = *(const half8*)&ipsk[(size_t)(b * NTOK + row - 84) * 640 + h * DH + c8 * 8];
        }
        *(half8*)&sK[row * ASTR + c8 * 8] = v;
    }
    for (int idx = tid; idx < 80 * 13; idx += 512) {
        int row = idx / 13, c8 = idx % 13;
        size_t g = (size_t)b * 640 + h * DH + row;
        half8 v = hz;
        if (c8 < 10) {
            v = *(const half8*)&vT[g * 80 + c8 * 8];
        } else if (c8 == 10) {
            half4 ip = *(const half4*)&ipvT[g * 4];
            v[0] = ip[0]; v[1] = ip[1]; v[2] = ip[2]; v[3] = ip[3];
        }
        *(half8*)&sVT[row * ASTR + c8 * 8] = v;
    }
    __syncthreads();

    const int lane = tid & 63;
    const int w = tid >> 6;                     // 0..7
    const int rb = w * 16;                      // sP row base (0..112)
    const int lrow = lane & 15, lhi = lane >> 4;
    const bool t4ok = (64 + lrow) < 77;

    for (int it = 0; it < 2; ++it) {
        const int qrow = q0 + it * 128 + rb;    // this wave's global q base

        const _Float16* qbase = qh + (size_t)(b * SS + qrow + lrow) * 640 + h * DH + lhi * 8;
        half8 a0 = *(const half8*)(qbase);
        half8 a1 = *(const half8*)(qbase + 32);
        half8 a2 = (lhi < 2) ? *(const half8*)(qbase + 64) : hz;

        f32x4 acc[6];
        #pragma unroll
        for (int nt = 0; nt < 6; ++nt) acc[nt] = (f32x4){0.f, 0.f, 0.f, 0.f};

        #pragma unroll
        for (int nt = 0; nt < 6; ++nt) {
            const _Float16* kb = &sK[(nt * 16 + lrow) * ASTR + lhi * 8];
            acc[nt] = __builtin_amdgcn_mfma_f32_16x16x32_f16(a0, *(const half8*)(kb),      acc[nt], 0, 0, 0);
            acc[nt] = __builtin_amdgcn_mfma_f32_16x16x32_f16(a1, *(const half8*)(kb + 32), acc[nt], 0, 0, 0);
            acc[nt] = __builtin_amdgcn_mfma_f32_16x16x32_f16(a2, *(const half8*)(kb + 64), acc[nt], 0, 0, 0);
        }

        #pragma unroll
        for (int nt = 0; nt < 6; ++nt) acc[nt] = acc[nt] * scale;

        #pragma unroll
        for (int r = 0; r < 4; ++r) {
            float e0 = __expf(acc[0][r]), e1 = __expf(acc[1][r]);
            float e2 = __expf(acc[2][r]), e3 = __expf(acc[3][r]);
            float e4 = t4ok ? __expf(acc[4][r]) : 0.f;
            float sm = e0 + e1 + e2 + e3 + e4;
            sm += __shfl_xor(sm, 1); sm += __shfl_xor(sm, 2);
            sm += __shfl_xor(sm, 4); sm += __shfl_xor(sm, 8);
            float inv = 1.f / sm;
            acc[0][r] = e0 * inv; acc[1][r] = e1 * inv; acc[2][r] = e2 * inv;
            acc[3][r] = e3 * inv; acc[4][r] = e4 * inv;

            float e5 = __expf(acc[5][r]);
            float sm5 = e5 + __shfl_xor(e5, 1);
            sm5 += __shfl_xor(sm5, 2);
            float p5 = e5 / sm5;
            float po = __shfl_xor(p5, 4);
            int gq = qrow + lhi * 4 + r;
            float fac = (mask[gq] != 0) ? 0.01f : 1.0f;
            float pc = fmaxf(p5, po) * fac;
            acc[5][r] = (lrow < 4) ? pc : 0.f;
        }

        #pragma unroll
        for (int nt = 0; nt < 6; ++nt)
            #pragma unroll
            for (int r = 0; r < 4; ++r)
                sP[(rb + lhi * 4 + r) * ASTR + nt * 16 + lrow] = (_Float16)acc[nt][r];

        f32x4 o[5];
        #pragma unroll
        for (int nt = 0; nt < 5; ++nt) o[nt] = (f32x4){0.f, 0.f, 0.f, 0.f};
        {
            const _Float16* pbase = &sP[(rb + lrow) * ASTR + lhi * 8];
            half8 p0 = *(const half8*)(pbase);
            half8 p1 = *(const half8*)(pbase + 32);
            half8 p2 = *(const half8*)(pbase + 64);
            #pragma unroll
            for (int nt = 0; nt < 5; ++nt) {
                const _Float16* vb = &sVT[(nt * 16 + lrow) * ASTR + lhi * 8];
                o[nt] = __builtin_amdgcn_mfma_f32_16x16x32_f16(p0, *(const half8*)(vb),      o[nt], 0, 0, 0);
                o[nt] = __builtin_amdgcn_mfma_f32_16x16x32_f16(p1, *(const half8*)(vb + 32), o[nt], 0, 0, 0);
                o[nt] = __builtin_amdgcn_mfma_f32_16x16x32_f16(p2, *(const half8*)(vb + 64), o[nt], 0, 0, 0);
            }
        }

        #pragma unroll
        for (int nt = 0; nt < 5; ++nt)
            #pragma unroll
            for (int r = 0; r < 4; ++r)
                attnout[(size_t)(b * SS + qrow + lhi * 4 + r) * 640 + h * DH + nt * 16 + lrow] =
                    (_Float16)o[nt][r];
    }
}

// ---------------------------------------------------------------- launch
extern "C" void kernel_launch(void* const* d_in, const int* in_sizes, int n_in,
                              void* d_out, int out_size, void* d_ws, size_t ws_size,
                              hipStream_t stream) {
    const float* hidden = (const float*)d_in[0];
    const float* ehs    = (const float*)d_in[1];
    const int*   mask   = (const int*)d_in[2];
    const float* Wq     = (const float*)d_in[3];
    const float* Wk     = (const float*)d_in[4];
    const float* Wv     = (const float*)d_in[5];
    const float* Wkip   = (const float*)d_in[6];
    const float* Wvip   = (const float*)d_in[7];
    const float* Wksip  = (const float*)d_in[8];
    const float* Wo     = (const float*)d_in[9];
    const float* bo     = (const float*)d_in[10];

    // ws layout (total 87,255,040 B, proven footprint):
    //   region A @ 0: ehs16 (1,044,480) + 5 x WT (983,040 ea) = 5,959,680
    //     dead after proj_and_convert; qhA (first written by gemm0) overlays it.
    //   qhA    0           41,943,040   q -> attn out (in-place)
    //   hid16  41,943,040  41,943,040
    //   BqT    83,886,080     819,200
    //   BoT    84,705,280     819,200
    //   ktxt   85,524,480     788,480
    //   vT     86,312,960     819,200   [b*640+d][80]
    //   ipk    87,132,160      40,960
    //   ipvT   87,173,120      40,960   [b*640+d][4]
    //   ipsk   87,214,080      40,960   -> ends 87,255,040
    char* ws = (char*)d_ws;
    _Float16* qhA    = (_Float16*)(ws);
    _Float16* ehs16  = (_Float16*)(ws);                      // overlaid by qhA later
    _Float16* WkT    = (_Float16*)(ws + 1044480);
    _Float16* WvT    = (_Float16*)(ws + 2027520);
    _Float16* WkipT  = (_Float16*)(ws + 3010560);
    _Float16* WvipT  = (_Float16*)(ws + 3993600);
    _Float16* WksipT = (_Float16*)(ws + 4976640);            // region A ends 5,959,680
    _Float16* hid16  = (_Float16*)(ws + 41943040);
    _Float16* BqT    = (_Float16*)(ws + 83886080);
    _Float16* BoT    = (_Float16*)(ws + 84705280);
    _Float16* ktxt   = (_Float16*)(ws + 85524480);
    _Float16* vT     = (_Float16*)(ws + 86312960);
    _Float16* ipk    = (_Float16*)(ws + 87132160);
    _Float16* ipvT   = (_Float16*)(ws + 87173120);
    _Float16* ipsk   = (_Float16*)(ws + 87214080);

    mega_convert<<<1055, 256, 0, stream>>>(ehs, ehs16, Wq, BqT, Wo, BoT,
                                           Wk, Wv, Wkip, Wvip, Wksip,
                                           WkT, WvT, WkipT, WvipT, WksipT);
    proj_and_convert<<<10470, 256, 0, stream>>>(ehs16, WkT, WvT, WkipT, WvipT, WksipT,
                                                ktxt, vT, ipk, ipvT, ipsk,
                                                hidden, hid16);
    gemm_f16<0><<<1280, 256, 0, stream>>>(hid16, BqT, nullptr, nullptr, qhA);
    attn_kernel<<<dim3(16, 64), 512, 0, stream>>>(qhA, ktxt, vT, ipk, ipvT, ipsk, mask, qhA);
    gemm_f16<1><<<1280, 256, 0, stream>>>(qhA, BoT, bo, hid16, d_out);
}

// Round 19
// 142.305 us; speedup vs baseline: 1.2146x; 1.0855x over previous
//
#include <hip/hip_runtime.h>
#include <hip/hip_bf16.h>
#include <hip/hip_fp16.h>

#define BB 8
#define SS 4096
#define CC 640
#define CDIM 768
#define LTXT 77
#define NTOK 4
#define DH 80
#define ASTR 104   // padded LDS row stride (f16) for attention tiles

typedef __attribute__((ext_vector_type(8))) _Float16 half8;
typedef __attribute__((ext_vector_type(4))) _Float16 half4;
typedef __attribute__((ext_vector_type(4))) float f32x4;

__device__ inline void gload_lds16(const void* g, void* l) {
    __builtin_amdgcn_global_load_lds((__attribute__((address_space(1))) void*)g,
                                     (__attribute__((address_space(3))) void*)l, 16, 0, 0);
}

// ---------------------------------------------------------------- mega convert
// One launch for all small converts. Job ranges on blockIdx.x:
//   [0,255)      ehs f32 -> ehs16           (255 blocks, 65280 x8 elems)
//   [255,355)    Wq[640][640] -> BqT[n][k]  (10 x 10 tiles)
//   [355,455)    Wo[640][640] -> BoT[n][k]
//   [455,1055)   5 proj weights [768][640] -> WT[640][768] (5 x 120 tiles)
__global__ __launch_bounds__(256)
void mega_convert(const float* __restrict__ ehs, _Float16* __restrict__ ehs16,
                  const float* __restrict__ Wq, _Float16* __restrict__ BqT,
                  const float* __restrict__ Wo, _Float16* __restrict__ BoT,
                  const float* __restrict__ W0, const float* __restrict__ W1,
                  const float* __restrict__ W2, const float* __restrict__ W3,
                  const float* __restrict__ W4,
                  _Float16* __restrict__ T0, _Float16* __restrict__ T1,
                  _Float16* __restrict__ T2, _Float16* __restrict__ T3,
                  _Float16* __restrict__ T4)
{
    __shared__ float t[64][65];
    const int z = blockIdx.x;
    const int tid = threadIdx.x;

    if (z < 255) {                      // ehs convert (no LDS)
        int i = z * 256 + tid;
        const float4* p = (const float4*)(ehs + (size_t)i * 8);
        float4 a = p[0], b = p[1];
        half8 h = {(_Float16)a.x, (_Float16)a.y, (_Float16)a.z, (_Float16)a.w,
                   (_Float16)b.x, (_Float16)b.y, (_Float16)b.z, (_Float16)b.w};
        *(half8*)(ehs16 + (size_t)i * 8) = h;
        return;
    }

    const float* W; _Float16* T; int n0, k0, Kdim;
    if (z < 455) {                      // 640x640 transposes
        int j = z - 255;
        W = (j < 100) ? Wq : Wo;
        T = (j < 100) ? BqT : BoT;
        j %= 100;
        n0 = (j / 10) * 64; k0 = (j % 10) * 64; Kdim = 640;
    } else {                            // 768x640 proj-weight transposes
        int j = z - 455;
        int wsel = j / 120, rem = j % 120;
        W = (wsel == 0) ? W0 : (wsel == 1) ? W1 : (wsel == 2) ? W2 : (wsel == 3) ? W3 : W4;
        T = (wsel == 0) ? T0 : (wsel == 1) ? T1 : (wsel == 2) ? T2 : (wsel == 3) ? T3 : T4;
        n0 = (rem % 10) * 64; k0 = (rem / 10) * 64; Kdim = CDIM;
    }
    for (int idx = tid; idx < 64 * 64; idx += 256) {
        int kk = idx >> 6, nn = idx & 63;
        t[kk][nn] = W[(size_t)(k0 + kk) * 640 + n0 + nn];
    }
    __syncthreads();
    for (int idx = tid; idx < 64 * 64; idx += 256) {
        int nn = idx >> 6, kk = idx & 63;
        T[(size_t)(n0 + nn) * Kdim + k0 + kk] = (_Float16)t[kk][nn];
    }
}

// ---------------------------------------------------------------- proj GEMM + hidden convert (fused launch)
// Blocks [0,230): projection MFMA GEMM. Blocks [230,10470): hidden f32->f16.
__global__ __launch_bounds__(256)
void proj_and_convert(const _Float16* __restrict__ A16,
                      const _Float16* __restrict__ WT0, const _Float16* __restrict__ WT1,
                      const _Float16* __restrict__ WT2, const _Float16* __restrict__ WT3,
                      const _Float16* __restrict__ WT4,
                      _Float16* __restrict__ O0, _Float16* __restrict__ O1,
                      _Float16* __restrict__ O2, _Float16* __restrict__ O3,
                      _Float16* __restrict__ O4,
                      const float* __restrict__ hidden, _Float16* __restrict__ hid16)
{
    __shared__ __align__(16) _Float16 sA[64 * 64];
    __shared__ __align__(16) _Float16 sB[64 * 64];
    const int tid = threadIdx.x;

    if (blockIdx.x >= 230) {            // hidden convert branch
        int i = (blockIdx.x - 230) * 256 + tid;
        if (i < 2621440) {
            const float4* p = (const float4*)(hidden + (size_t)i * 8);
            float4 a = p[0], b = p[1];
            half8 h = {(_Float16)a.x, (_Float16)a.y, (_Float16)a.z, (_Float16)a.w,
                       (_Float16)b.x, (_Float16)b.y, (_Float16)b.z, (_Float16)b.w};
            *(half8*)(hid16 + (size_t)i * 8) = h;
        }
        return;
    }

    const int job = blockIdx.x;
    int wsel, mtile, ntile;
    if (job < 200) { wsel = job / 100; mtile = (job % 100) / 10; ntile = job % 10; }
    else { int j = job - 200; wsel = 2 + j / 10; mtile = 0; ntile = j % 10; }
    const _Float16* WT = (wsel == 0) ? WT0 : (wsel == 1) ? WT1 : (wsel == 2) ? WT2 : (wsel == 3) ? WT3 : WT4;
    const int Mv = (wsel < 2) ? 616 : 32;
    const int bm = mtile * 64, bn = ntile * 64;

    const _Float16* asrc[2];
    const _Float16* bsrc[2];
    int sslot[2];
    #pragma unroll
    for (int p = 0; p < 2; ++p) {
        int s = p * 256 + tid;
        int row = s >> 3, sub = s & 7;
        int c = sub ^ (row & 7);
        int m = bm + row; if (m > Mv - 1) m = Mv - 1;
        int srcrow;
        if (wsel < 2) srcrow = (m / 77) * 85 + (m % 77);
        else { int b2 = m >> 2, t2 = m & 3; srcrow = b2 * 85 + ((wsel == 4) ? 81 : 77) + t2; }
        asrc[p] = A16 + (size_t)srcrow * CDIM + c * 8;
        bsrc[p] = WT + (size_t)(bn + row) * CDIM + c * 8;
        sslot[p] = s * 8;
    }

    const int lane = tid & 63, w = tid >> 6;
    const int wm = w >> 1, wn = w & 1;
    const int lrow = lane & 15, lhi = lane >> 4;

    f32x4 acc[2][2];
    #pragma unroll
    for (int mt = 0; mt < 2; ++mt)
        #pragma unroll
        for (int nt = 0; nt < 2; ++nt)
            acc[mt][nt] = (f32x4){0.f, 0.f, 0.f, 0.f};

    for (int k0 = 0; k0 < CDIM; k0 += 64) {
        #pragma unroll
        for (int p = 0; p < 2; ++p) {
            gload_lds16(asrc[p] + k0, sA + sslot[p]);
            gload_lds16(bsrc[p] + k0, sB + sslot[p]);
        }
        __syncthreads();
        #pragma unroll
        for (int ks = 0; ks < 2; ++ks) {
            half8 af[2], bf[2];
            #pragma unroll
            for (int mt = 0; mt < 2; ++mt) {
                int row = wm * 32 + mt * 16 + lrow;
                int sub = (ks * 4 + lhi) ^ (row & 7);
                af[mt] = *(const half8*)&sA[row * 64 + sub * 8];
            }
            #pragma unroll
            for (int nt = 0; nt < 2; ++nt) {
                int row = wn * 32 + nt * 16 + lrow;
                int sub = (ks * 4 + lhi) ^ (row & 7);
                bf[nt] = *(const half8*)&sB[row * 64 + sub * 8];
            }
            #pragma unroll
            for (int mt = 0; mt < 2; ++mt)
                #pragma unroll
                for (int nt = 0; nt < 2; ++nt)
                    acc[mt][nt] = __builtin_amdgcn_mfma_f32_16x16x32_f16(af[mt], bf[nt], acc[mt][nt], 0, 0, 0);
        }
        __syncthreads();
    }

    _Float16* Op = (wsel == 0) ? O0 : (wsel == 2) ? O2 : O4;
    #pragma unroll
    for (int mt = 0; mt < 2; ++mt) {
        #pragma unroll
        for (int nt = 0; nt < 2; ++nt) {
            int col = bn + wn * 32 + nt * 16 + lrow;
            #pragma unroll
            for (int r = 0; r < 4; ++r) {
                int m = bm + wm * 32 + mt * 16 + lhi * 4 + r;
                if (m < Mv) {
                    _Float16 val = (_Float16)acc[mt][nt][r];
                    if (wsel == 1) {
                        int bb = m / 77, j = m % 77;
                        O1[((size_t)bb * 640 + col) * 80 + j] = val;
                    } else if (wsel == 3) {
                        int bb = m >> 2, t = m & 3;
                        O3[((size_t)bb * 640 + col) * 4 + t] = val;
                    } else {
                        Op[(size_t)m * 640 + col] = val;
                    }
                }
            }
        }
    }
}

// ---------------------------------------------------------------- f16 MFMA GEMM (2-phase dbuf, 128x160 tile)
// C[M,640] = A[M,640] @ BT[640,640]^T. Tile 128x160 (N = 4 x 160):
//  - 40 MFMA / 18.4 KB staged per K-tile (vs 32/16 at 128x128): +11% density
//  - grid 1024 = 2 blocks/CU x 256 CU x 2 -> EXACTLY 2 residency rounds
//    (128x128 had 1280 blocks = 2.5 rounds, 50%-empty tail)
//  - LDS 73.7 KB (2 blocks/CU), VGPR ~120 (4 waves/SIMD, no forced cap —
//    round 9 showed capping to 5 blocks spills acc to accvgpr)
// Schedule unchanged from round 14: stage tile t+1 FIRST, compute t, ONE
// barrier per tile. XCD-bijective swizzle (1024 = 8 x 128), n-inner (4).
// EPI 0: f16 store. EPI 1: 0.5*(acc+bias)+resid16, f32 store (resid is f16).
template<int EPI>
__global__ __launch_bounds__(256)
void gemm_f16(const _Float16* __restrict__ A, const _Float16* __restrict__ BT,
              const float* __restrict__ bias, const _Float16* __restrict__ resid,
              void* __restrict__ Cp)
{
    __shared__ __align__(16) _Float16 sA[2][128 * 64];
    __shared__ __align__(16) _Float16 sB[2][160 * 64];

    const int tid = threadIdx.x;
    const int lane = tid & 63;
    const int w = tid >> 6, wm = w >> 1, wn = w & 1;
    const int lrow = lane & 15, lhi = lane >> 4;

    const int orig = blockIdx.x;
    const int wgid = (orig & 7) * 128 + (orig >> 3);
    const int bm = (wgid >> 2) * 128, bn = (wgid & 3) * 160;

    // staging sources: A 1024 slots (p<4), B 1280 slots (p<5)
    const _Float16* asrc[4];
    int aslot[4];
    #pragma unroll
    for (int p = 0; p < 4; ++p) {
        int s = p * 256 + tid;
        int row = s >> 3, sub = s & 7;
        int c = sub ^ (row & 7);                // inverse-swizzled source
        asrc[p] = A + (size_t)(bm + row) * 640 + c * 8;
        aslot[p] = s * 8;
    }
    const _Float16* bsrc[5];
    int bslot[5];
    #pragma unroll
    for (int p = 0; p < 5; ++p) {
        int s = p * 256 + tid;
        int row = s >> 3, sub = s & 7;
        int c = sub ^ (row & 7);
        bsrc[p] = BT + (size_t)(bn + row) * 640 + c * 8;
        bslot[p] = s * 8;
    }

    f32x4 acc[4][5];
    #pragma unroll
    for (int mt = 0; mt < 4; ++mt)
        #pragma unroll
        for (int nt = 0; nt < 5; ++nt)
            acc[mt][nt] = (f32x4){0.f, 0.f, 0.f, 0.f};

    #pragma unroll
    for (int p = 0; p < 4; ++p) gload_lds16(asrc[p], &sA[0][aslot[p]]);
    #pragma unroll
    for (int p = 0; p < 5; ++p) gload_lds16(bsrc[p], &sB[0][bslot[p]]);
    __syncthreads();

    for (int t = 0; t < 10; ++t) {
        const int cur = t & 1;
        if (t < 9) {
            const int k1 = (t + 1) * 64;
            #pragma unroll
            for (int p = 0; p < 4; ++p) gload_lds16(asrc[p] + k1, &sA[cur ^ 1][aslot[p]]);
            #pragma unroll
            for (int p = 0; p < 5; ++p) gload_lds16(bsrc[p] + k1, &sB[cur ^ 1][bslot[p]]);
        }
        __builtin_amdgcn_s_setprio(1);
        #pragma unroll
        for (int ks = 0; ks < 2; ++ks) {
            half8 af[4], bf[5];
            #pragma unroll
            for (int mt = 0; mt < 4; ++mt) {
                int row = wm * 64 + mt * 16 + lrow;
                int sub = (ks * 4 + lhi) ^ (row & 7);
                af[mt] = *(const half8*)&sA[cur][row * 64 + sub * 8];
            }
            #pragma unroll
            for (int nt = 0; nt < 5; ++nt) {
                int row = wn * 80 + nt * 16 + lrow;
                int sub = (ks * 4 + lhi) ^ (row & 7);
                bf[nt] = *(const half8*)&sB[cur][row * 64 + sub * 8];
            }
            #pragma unroll
            for (int mt = 0; mt < 4; ++mt)
                #pragma unroll
                for (int nt = 0; nt < 5; ++nt)
                    acc[mt][nt] = __builtin_amdgcn_mfma_f32_16x16x32_f16(af[mt], bf[nt], acc[mt][nt], 0, 0, 0);
        }
        __builtin_amdgcn_s_setprio(0);
        __syncthreads();
    }

    #pragma unroll
    for (int mt = 0; mt < 4; ++mt) {
        #pragma unroll
        for (int nt = 0; nt < 5; ++nt) {
            int row0 = bm + wm * 64 + mt * 16 + lhi * 4;
            int col = bn + wn * 80 + nt * 16 + lrow;
            #pragma unroll
            for (int r = 0; r < 4; ++r) {
                float v = acc[mt][nt][r];
                if (EPI == 0) {
                    ((_Float16*)Cp)[(size_t)(row0 + r) * 640 + col] = (_Float16)v;
                } else {
                    float o = 0.5f * (v + bias[col]) + (float)resid[(size_t)(row0 + r) * 640 + col];
                    ((float*)Cp)[(size_t)(row0 + r) * 640 + col] = o;
                }
            }
        }
    }
}

// ---------------------------------------------------------------- MFMA attention (8-wave blocks)
// Round-18 best config: per-wave code identical to the r14/17 optimum; 512
// threads = 8 waves x 16 q-rows x 2 iterations = 256 q per block. 16 waves/CU.
// Softmax without max-subtraction (scores small, f32-safe, identical result).
// K-pack rows: 0..76 text, 77..79 zero, 80..83 ip, 84..87 ips, 88..95 zero.
// attnout aliases qh (in-place): each wave reads exactly the q it overwrites.
__global__ __launch_bounds__(512)
void attn_kernel(const _Float16* __restrict__ qh,
                 const _Float16* __restrict__ ktxt, const _Float16* __restrict__ vT,
                 const _Float16* __restrict__ ipk, const _Float16* __restrict__ ipvT,
                 const _Float16* __restrict__ ipsk, const int* __restrict__ mask,
                 _Float16* __restrict__ attnout)
{
    __shared__ __align__(16) _Float16 sK[96 * ASTR];
    __shared__ __align__(16) _Float16 sVT[80 * ASTR];
    __shared__ __align__(16) _Float16 sP[128 * ASTR];

    const int q0 = blockIdx.x * 256;            // 256 q-rows per block
    const int bh = blockIdx.y;
    const int b = bh >> 3, h = bh & 7;
    const int tid = threadIdx.x;
    const float scale = 0.11180339887498948f;   // 1/sqrt(80)
    const half8 hz = {0, 0, 0, 0, 0, 0, 0, 0};

    for (int idx = tid; idx < 96 * 13; idx += 512) {
        int row = idx / 13, c8 = idx % 13;
        half8 v = hz;
        if (c8 < 10) {
            if (row < 77)                       v = *(const half8*)&ktxt[(size_t)(b * LTXT + row) * 640 + h * DH + c8 * 8];
            else if (row >= 80 && row < 84)     v = *(const half8*)&ipk [(size_t)(b * NTOK + row - 80) * 640 + h * DH + c8 * 8];
            else if (row >= 84 && row < 88)     v = *(const half8*)&ipsk[(size_t)(b * NTOK + row - 84) * 640 + h * DH + c8 * 8];
        }
        *(half8*)&sK[row * ASTR + c8 * 8] = v;
    }
    for (int idx = tid; idx < 80 * 13; idx += 512) {
        int row = idx / 13, c8 = idx % 13;
        size_t g = (size_t)b * 640 + h * DH + row;
        half8 v = hz;
        if (c8 < 10) {
            v = *(const half8*)&vT[g * 80 + c8 * 8];
        } else if (c8 == 10) {
            half4 ip = *(const half4*)&ipvT[g * 4];
            v[0] = ip[0]; v[1] = ip[1]; v[2] = ip[2]; v[3] = ip[3];
        }
        *(half8*)&sVT[row * ASTR + c8 * 8] = v;
    }
    __syncthreads();

    const int lane = tid & 63;
    const int w = tid >> 6;                     // 0..7
    const int rb = w * 16;                      // sP row base (0..112)
    const int lrow = lane & 15, lhi = lane >> 4;
    const bool t4ok = (64 + lrow) < 77;

    for (int it = 0; it < 2; ++it) {
        const int qrow = q0 + it * 128 + rb;    // this wave's global q base

        const _Float16* qbase = qh + (size_t)(b * SS + qrow + lrow) * 640 + h * DH + lhi * 8;
        half8 a0 = *(const half8*)(qbase);
        half8 a1 = *(const half8*)(qbase + 32);
        half8 a2 = (lhi < 2) ? *(const half8*)(qbase + 64) : hz;

        f32x4 acc[6];
        #pragma unroll
        for (int nt = 0; nt < 6; ++nt) acc[nt] = (f32x4){0.f, 0.f, 0.f, 0.f};

        #pragma unroll
        for (int nt = 0; nt < 6; ++nt) {
            const _Float16* kb = &sK[(nt * 16 + lrow) * ASTR + lhi * 8];
            acc[nt] = __builtin_amdgcn_mfma_f32_16x16x32_f16(a0, *(const half8*)(kb),      acc[nt], 0, 0, 0);
            acc[nt] = __builtin_amdgcn_mfma_f32_16x16x32_f16(a1, *(const half8*)(kb + 32), acc[nt], 0, 0, 0);
            acc[nt] = __builtin_amdgcn_mfma_f32_16x16x32_f16(a2, *(const half8*)(kb + 64), acc[nt], 0, 0, 0);
        }

        #pragma unroll
        for (int nt = 0; nt < 6; ++nt) acc[nt] = acc[nt] * scale;

        #pragma unroll
        for (int r = 0; r < 4; ++r) {
            float e0 = __expf(acc[0][r]), e1 = __expf(acc[1][r]);
            float e2 = __expf(acc[2][r]), e3 = __expf(acc[3][r]);
            float e4 = t4ok ? __expf(acc[4][r]) : 0.f;
            float sm = e0 + e1 + e2 + e3 + e4;
            sm += __shfl_xor(sm, 1); sm += __shfl_xor(sm, 2);
            sm += __shfl_xor(sm, 4); sm += __shfl_xor(sm, 8);
            float inv = 1.f / sm;
            acc[0][r] = e0 * inv; acc[1][r] = e1 * inv; acc[2][r] = e2 * inv;
            acc[3][r] = e3 * inv; acc[4][r] = e4 * inv;

            float e5 = __expf(acc[5][r]);
            float sm5 = e5 + __shfl_xor(e5, 1);
            sm5 += __shfl_xor(sm5, 2);
            float p5 = e5 / sm5;
            float po = __shfl_xor(p5, 4);
            int gq = qrow + lhi * 4 + r;
            float fac = (mask[gq] != 0) ? 0.01f : 1.0f;
            float pc = fmaxf(p5, po) * fac;
            acc[5][r] = (lrow < 4) ? pc : 0.f;
        }

        #pragma unroll
        for (int nt = 0; nt < 6; ++nt)
            #pragma unroll
            for (int r = 0; r < 4; ++r)
                sP[(rb + lhi * 4 + r) * ASTR + nt * 16 + lrow] = (_Float16)acc[nt][r];

        f32x4 o[5];
        #pragma unroll
        for (int nt = 0; nt < 5; ++nt) o[nt] = (f32x4){0.f, 0.f, 0.f, 0.f};
        {
            const _Float16* pbase = &sP[(rb + lrow) * ASTR + lhi * 8];
            half8 p0 = *(const half8*)(pbase);
            half8 p1 = *(const half8*)(pbase + 32);
            half8 p2 = *(const half8*)(pbase + 64);
            #pragma unroll
            for (int nt = 0; nt < 5; ++nt) {
                const _Float16* vb = &sVT[(nt * 16 + lrow) * ASTR + lhi * 8];
                o[nt] = __builtin_amdgcn_mfma_f32_16x16x32_f16(p0, *(const half8*)(vb),      o[nt], 0, 0, 0);
                o[nt] = __builtin_amdgcn_mfma_f32_16x16x32_f16(p1, *(const half8*)(vb + 32), o[nt], 0, 0, 0);
                o[nt] = __builtin_amdgcn_mfma_f32_16x16x32_f16(p2, *(const half8*)(vb + 64), o[nt], 0, 0, 0);
            }
        }

        #pragma unroll
        for (int nt = 0; nt < 5; ++nt)
            #pragma unroll
            for (int r = 0; r < 4; ++r)
                attnout[(size_t)(b * SS + qrow + lhi * 4 + r) * 640 + h * DH + nt * 16 + lrow] =
                    (_Float16)o[nt][r];
    }
}

// ---------------------------------------------------------------- launch
extern "C" void kernel_launch(void* const* d_in, const int* in_sizes, int n_in,
                              void* d_out, int out_size, void* d_ws, size_t ws_size,
                              hipStream_t stream) {
    const float* hidden = (const float*)d_in[0];
    const float* ehs    = (const float*)d_in[1];
    const int*   mask   = (const int*)d_in[2];
    const float* Wq     = (const float*)d_in[3];
    const float* Wk     = (const float*)d_in[4];
    const float* Wv     = (const float*)d_in[5];
    const float* Wkip   = (const float*)d_in[6];
    const float* Wvip   = (const float*)d_in[7];
    const float* Wksip  = (const float*)d_in[8];
    const float* Wo     = (const float*)d_in[9];
    const float* bo     = (const float*)d_in[10];

    // ws layout (total 87,255,040 B, proven footprint):
    //   region A @ 0: ehs16 (1,044,480) + 5 x WT (983,040 ea) = 5,959,680
    //     dead after proj_and_convert; qhA (first written by gemm0) overlays it.
    //   qhA    0           41,943,040   q -> attn out (in-place)
    //   hid16  41,943,040  41,943,040
    //   BqT    83,886,080     819,200
    //   BoT    84,705,280     819,200
    //   ktxt   85,524,480     788,480
    //   vT     86,312,960     819,200   [b*640+d][80]
    //   ipk    87,132,160      40,960
    //   ipvT   87,173,120      40,960   [b*640+d][4]
    //   ipsk   87,214,080      40,960   -> ends 87,255,040
    char* ws = (char*)d_ws;
    _Float16* qhA    = (_Float16*)(ws);
    _Float16* ehs16  = (_Float16*)(ws);                      // overlaid by qhA later
    _Float16* WkT    = (_Float16*)(ws + 1044480);
    _Float16* WvT    = (_Float16*)(ws + 2027520);
    _Float16* WkipT  = (_Float16*)(ws + 3010560);
    _Float16* WvipT  = (_Float16*)(ws + 3993600);
    _Float16* WksipT = (_Float16*)(ws + 4976640);            // region A ends 5,959,680
    _Float16* hid16  = (_Float16*)(ws + 41943040);
    _Float16* BqT    = (_Float16*)(ws + 83886080);
    _Float16* BoT    = (_Float16*)(ws + 84705280);
    _Float16* ktxt   = (_Float16*)(ws + 85524480);
    _Float16* vT     = (_Float16*)(ws + 86312960);
    _Float16* ipk    = (_Float16*)(ws + 87132160);
    _Float16* ipvT   = (_Float16*)(ws + 87173120);
    _Float16* ipsk   = (_Float16*)(ws + 87214080);

    mega_convert<<<1055, 256, 0, stream>>>(ehs, ehs16, Wq, BqT, Wo, BoT,
                                           Wk, Wv, Wkip, Wvip, Wksip,
                                           WkT, WvT, WkipT, WvipT, WksipT);
    proj_and_convert<<<10470, 256, 0, stream>>>(ehs16, WkT, WvT, WkipT, WvipT, WksipT,
                                                ktxt, vT, ipk, ipvT, ipsk,
                                                hidden, hid16);
    gemm_f16<0><<<1024, 256, 0, stream>>>(hid16, BqT, nullptr, nullptr, qhA);
    attn_kernel<<<dim3(16, 64), 512, 0, stream>>>(qhA, ktxt, vT, ipk, ipvT, ipsk, mask, qhA);
    gemm_f16<1><<<1024, 256, 0, stream>>>(qhA, BoT, bo, hid16, d_out);
}

// Round 20
// 134.469 us; speedup vs baseline: 1.2854x; 1.0583x over previous
//
#include <hip/hip_runtime.h>
#include <hip/hip_bf16.h>
#include <hip/hip_fp16.h>

#define BB 8
#define SS 4096
#define CC 640
#define CDIM 768
#define LTXT 77
#define NTOK 4
#define DH 80
#define ASTR 104   // padded LDS row stride (f16) for attention tiles

typedef __attribute__((ext_vector_type(8))) _Float16 half8;
typedef __attribute__((ext_vector_type(4))) _Float16 half4;
typedef __attribute__((ext_vector_type(4))) float f32x4;

__device__ inline void gload_lds16(const void* g, void* l) {
    __builtin_amdgcn_global_load_lds((__attribute__((address_space(1))) void*)g,
                                     (__attribute__((address_space(3))) void*)l, 16, 0, 0);
}

// ---------------------------------------------------------------- mega convert
// One launch for all small converts. Job ranges on blockIdx.x:
//   [0,255)      ehs f32 -> ehs16           (255 blocks, 65280 x8 elems)
//   [255,355)    Wq[640][640] -> BqT[n][k]  (10 x 10 tiles)
//   [355,455)    Wo[640][640] -> BoT[n][k]
//   [455,1055)   5 proj weights [768][640] -> WT[640][768] (5 x 120 tiles)
__global__ __launch_bounds__(256)
void mega_convert(const float* __restrict__ ehs, _Float16* __restrict__ ehs16,
                  const float* __restrict__ Wq, _Float16* __restrict__ BqT,
                  const float* __restrict__ Wo, _Float16* __restrict__ BoT,
                  const float* __restrict__ W0, const float* __restrict__ W1,
                  const float* __restrict__ W2, const float* __restrict__ W3,
                  const float* __restrict__ W4,
                  _Float16* __restrict__ T0, _Float16* __restrict__ T1,
                  _Float16* __restrict__ T2, _Float16* __restrict__ T3,
                  _Float16* __restrict__ T4)
{
    __shared__ float t[64][65];
    const int z = blockIdx.x;
    const int tid = threadIdx.x;

    if (z < 255) {                      // ehs convert (no LDS)
        int i = z * 256 + tid;
        const float4* p = (const float4*)(ehs + (size_t)i * 8);
        float4 a = p[0], b = p[1];
        half8 h = {(_Float16)a.x, (_Float16)a.y, (_Float16)a.z, (_Float16)a.w,
                   (_Float16)b.x, (_Float16)b.y, (_Float16)b.z, (_Float16)b.w};
        *(half8*)(ehs16 + (size_t)i * 8) = h;
        return;
    }

    const float* W; _Float16* T; int n0, k0, Kdim;
    if (z < 455) {                      // 640x640 transposes
        int j = z - 255;
        W = (j < 100) ? Wq : Wo;
        T = (j < 100) ? BqT : BoT;
        j %= 100;
        n0 = (j / 10) * 64; k0 = (j % 10) * 64; Kdim = 640;
    } else {                            // 768x640 proj-weight transposes
        int j = z - 455;
        int wsel = j / 120, rem = j % 120;
        W = (wsel == 0) ? W0 : (wsel == 1) ? W1 : (wsel == 2) ? W2 : (wsel == 3) ? W3 : W4;
        T = (wsel == 0) ? T0 : (wsel == 1) ? T1 : (wsel == 2) ? T2 : (wsel == 3) ? T3 : T4;
        n0 = (rem % 10) * 64; k0 = (rem / 10) * 64; Kdim = CDIM;
    }
    for (int idx = tid; idx < 64 * 64; idx += 256) {
        int kk = idx >> 6, nn = idx & 63;
        t[kk][nn] = W[(size_t)(k0 + kk) * 640 + n0 + nn];
    }
    __syncthreads();
    for (int idx = tid; idx < 64 * 64; idx += 256) {
        int nn = idx >> 6, kk = idx & 63;
        T[(size_t)(n0 + nn) * Kdim + k0 + kk] = (_Float16)t[kk][nn];
    }
}

// ---------------------------------------------------------------- proj GEMM + hidden convert (fused launch)
// Blocks [0,230): projection MFMA GEMM. Blocks [230,10470): hidden f32->f16.
__global__ __launch_bounds__(256)
void proj_and_convert(const _Float16* __restrict__ A16,
                      const _Float16* __restrict__ WT0, const _Float16* __restrict__ WT1,
                      const _Float16* __restrict__ WT2, const _Float16* __restrict__ WT3,
                      const _Float16* __restrict__ WT4,
                      _Float16* __restrict__ O0, _Float16* __restrict__ O1,
                      _Float16* __restrict__ O2, _Float16* __restrict__ O3,
                      _Float16* __restrict__ O4,
                      const float* __restrict__ hidden, _Float16* __restrict__ hid16)
{
    __shared__ __align__(16) _Float16 sA[64 * 64];
    __shared__ __align__(16) _Float16 sB[64 * 64];
    const int tid = threadIdx.x;

    if (blockIdx.x >= 230) {            // hidden convert branch
        int i = (blockIdx.x - 230) * 256 + tid;
        if (i < 2621440) {
            const float4* p = (const float4*)(hidden + (size_t)i * 8);
            float4 a = p[0], b = p[1];
            half8 h = {(_Float16)a.x, (_Float16)a.y, (_Float16)a.z, (_Float16)a.w,
                       (_Float16)b.x, (_Float16)b.y, (_Float16)b.z, (_Float16)b.w};
            *(half8*)(hid16 + (size_t)i * 8) = h;
        }
        return;
    }

    const int job = blockIdx.x;
    int wsel, mtile, ntile;
    if (job < 200) { wsel = job / 100; mtile = (job % 100) / 10; ntile = job % 10; }
    else { int j = job - 200; wsel = 2 + j / 10; mtile = 0; ntile = j % 10; }
    const _Float16* WT = (wsel == 0) ? WT0 : (wsel == 1) ? WT1 : (wsel == 2) ? WT2 : (wsel == 3) ? WT3 : WT4;
    const int Mv = (wsel < 2) ? 616 : 32;
    const int bm = mtile * 64, bn = ntile * 64;

    const _Float16* asrc[2];
    const _Float16* bsrc[2];
    int sslot[2];
    #pragma unroll
    for (int p = 0; p < 2; ++p) {
        int s = p * 256 + tid;
        int row = s >> 3, sub = s & 7;
        int c = sub ^ (row & 7);
        int m = bm + row; if (m > Mv - 1) m = Mv - 1;
        int srcrow;
        if (wsel < 2) srcrow = (m / 77) * 85 + (m % 77);
        else { int b2 = m >> 2, t2 = m & 3; srcrow = b2 * 85 + ((wsel == 4) ? 81 : 77) + t2; }
        asrc[p] = A16 + (size_t)srcrow * CDIM + c * 8;
        bsrc[p] = WT + (size_t)(bn + row) * CDIM + c * 8;
        sslot[p] = s * 8;
    }

    const int lane = tid & 63, w = tid >> 6;
    const int wm = w >> 1, wn = w & 1;
    const int lrow = lane & 15, lhi = lane >> 4;

    f32x4 acc[2][2];
    #pragma unroll
    for (int mt = 0; mt < 2; ++mt)
        #pragma unroll
        for (int nt = 0; nt < 2; ++nt)
            acc[mt][nt] = (f32x4){0.f, 0.f, 0.f, 0.f};

    for (int k0 = 0; k0 < CDIM; k0 += 64) {
        #pragma unroll
        for (int p = 0; p < 2; ++p) {
            gload_lds16(asrc[p] + k0, sA + sslot[p]);
            gload_lds16(bsrc[p] + k0, sB + sslot[p]);
        }
        __syncthreads();
        #pragma unroll
        for (int ks = 0; ks < 2; ++ks) {
            half8 af[2], bf[2];
            #pragma unroll
            for (int mt = 0; mt < 2; ++mt) {
                int row = wm * 32 + mt * 16 + lrow;
                int sub = (ks * 4 + lhi) ^ (row & 7);
                af[mt] = *(const half8*)&sA[row * 64 + sub * 8];
            }
            #pragma unroll
            for (int nt = 0; nt < 2; ++nt) {
                int row = wn * 32 + nt * 16 + lrow;
                int sub = (ks * 4 + lhi) ^ (row & 7);
                bf[nt] = *(const half8*)&sB[row * 64 + sub * 8];
            }
            #pragma unroll
            for (int mt = 0; mt < 2; ++mt)
                #pragma unroll
                for (int nt = 0; nt < 2; ++nt)
                    acc[mt][nt] = __builtin_amdgcn_mfma_f32_16x16x32_f16(af[mt], bf[nt], acc[mt][nt], 0, 0, 0);
        }
        __syncthreads();
    }

    _Float16* Op = (wsel == 0) ? O0 : (wsel == 2) ? O2 : O4;
    #pragma unroll
    for (int mt = 0; mt < 2; ++mt) {
        #pragma unroll
        for (int nt = 0; nt < 2; ++nt) {
            int col = bn + wn * 32 + nt * 16 + lrow;
            #pragma unroll
            for (int r = 0; r < 4; ++r) {
                int m = bm + wm * 32 + mt * 16 + lhi * 4 + r;
                if (m < Mv) {
                    _Float16 val = (_Float16)acc[mt][nt][r];
                    if (wsel == 1) {
                        int bb = m / 77, j = m % 77;
                        O1[((size_t)bb * 640 + col) * 80 + j] = val;
                    } else if (wsel == 3) {
                        int bb = m >> 2, t = m & 3;
                        O3[((size_t)bb * 640 + col) * 4 + t] = val;
                    } else {
                        Op[(size_t)m * 640 + col] = val;
                    }
                }
            }
        }
    }
}

// ---------------------------------------------------------------- f16 MFMA GEMM (2-phase dbuf, 128x160 tile)
// C[M,640] = A[M,640] @ BT[640,640]^T. Tile 128x160 (N = 4 x 160):
// 40 MFMA / 18.4 KB staged per K-tile; grid 1024 = exactly 2 residency rounds;
// LDS 73.7 KB (2 blocks/CU). Round 19: -12 us vs 128x128.
// Schedule: stage tile t+1 FIRST, compute t, ONE barrier per tile (round 14).
// XCD-bijective swizzle (1024 = 8 x 128), n-inner (4 n-tiles per A panel).
// EPI 0: f16 store. EPI 1: 0.5*(acc+bias)+resid16, f32 store (resid is f16).
template<int EPI>
__global__ __launch_bounds__(256)
void gemm_f16(const _Float16* __restrict__ A, const _Float16* __restrict__ BT,
              const float* __restrict__ bias, const _Float16* __restrict__ resid,
              void* __restrict__ Cp)
{
    __shared__ __align__(16) _Float16 sA[2][128 * 64];
    __shared__ __align__(16) _Float16 sB[2][160 * 64];

    const int tid = threadIdx.x;
    const int lane = tid & 63;
    const int w = tid >> 6, wm = w >> 1, wn = w & 1;
    const int lrow = lane & 15, lhi = lane >> 4;

    const int orig = blockIdx.x;
    const int wgid = (orig & 7) * 128 + (orig >> 3);
    const int bm = (wgid >> 2) * 128, bn = (wgid & 3) * 160;

    const _Float16* asrc[4];
    int aslot[4];
    #pragma unroll
    for (int p = 0; p < 4; ++p) {
        int s = p * 256 + tid;
        int row = s >> 3, sub = s & 7;
        int c = sub ^ (row & 7);                // inverse-swizzled source
        asrc[p] = A + (size_t)(bm + row) * 640 + c * 8;
        aslot[p] = s * 8;
    }
    const _Float16* bsrc[5];
    int bslot[5];
    #pragma unroll
    for (int p = 0; p < 5; ++p) {
        int s = p * 256 + tid;
        int row = s >> 3, sub = s & 7;
        int c = sub ^ (row & 7);
        bsrc[p] = BT + (size_t)(bn + row) * 640 + c * 8;
        bslot[p] = s * 8;
    }

    f32x4 acc[4][5];
    #pragma unroll
    for (int mt = 0; mt < 4; ++mt)
        #pragma unroll
        for (int nt = 0; nt < 5; ++nt)
            acc[mt][nt] = (f32x4){0.f, 0.f, 0.f, 0.f};

    #pragma unroll
    for (int p = 0; p < 4; ++p) gload_lds16(asrc[p], &sA[0][aslot[p]]);
    #pragma unroll
    for (int p = 0; p < 5; ++p) gload_lds16(bsrc[p], &sB[0][bslot[p]]);
    __syncthreads();

    for (int t = 0; t < 10; ++t) {
        const int cur = t & 1;
        if (t < 9) {
            const int k1 = (t + 1) * 64;
            #pragma unroll
            for (int p = 0; p < 4; ++p) gload_lds16(asrc[p] + k1, &sA[cur ^ 1][aslot[p]]);
            #pragma unroll
            for (int p = 0; p < 5; ++p) gload_lds16(bsrc[p] + k1, &sB[cur ^ 1][bslot[p]]);
        }
        __builtin_amdgcn_s_setprio(1);
        #pragma unroll
        for (int ks = 0; ks < 2; ++ks) {
            half8 af[4], bf[5];
            #pragma unroll
            for (int mt = 0; mt < 4; ++mt) {
                int row = wm * 64 + mt * 16 + lrow;
                int sub = (ks * 4 + lhi) ^ (row & 7);
                af[mt] = *(const half8*)&sA[cur][row * 64 + sub * 8];
            }
            #pragma unroll
            for (int nt = 0; nt < 5; ++nt) {
                int row = wn * 80 + nt * 16 + lrow;
                int sub = (ks * 4 + lhi) ^ (row & 7);
                bf[nt] = *(const half8*)&sB[cur][row * 64 + sub * 8];
            }
            #pragma unroll
            for (int mt = 0; mt < 4; ++mt)
                #pragma unroll
                for (int nt = 0; nt < 5; ++nt)
                    acc[mt][nt] = __builtin_amdgcn_mfma_f32_16x16x32_f16(af[mt], bf[nt], acc[mt][nt], 0, 0, 0);
        }
        __builtin_amdgcn_s_setprio(0);
        __syncthreads();
    }

    #pragma unroll
    for (int mt = 0; mt < 4; ++mt) {
        #pragma unroll
        for (int nt = 0; nt < 5; ++nt) {
            int row0 = bm + wm * 64 + mt * 16 + lhi * 4;
            int col = bn + wn * 80 + nt * 16 + lrow;
            #pragma unroll
            for (int r = 0; r < 4; ++r) {
                float v = acc[mt][nt][r];
                if (EPI == 0) {
                    ((_Float16*)Cp)[(size_t)(row0 + r) * 640 + col] = (_Float16)v;
                } else {
                    float o = 0.5f * (v + bias[col]) + (float)resid[(size_t)(row0 + r) * 640 + col];
                    ((float*)Cp)[(size_t)(row0 + r) * 640 + col] = o;
                }
            }
        }
    }
}

// ---------------------------------------------------------------- MFMA attention (8-wave blocks, 4 iters)
// Per-wave code identical to the r14/17 optimum. 512 threads = 8 waves x 16
// q-rows x 4 iterations = 512 q per block; grid 8x64 = 512 blocks = EXACTLY
// one residency round (2 blocks/CU x 256 CU), K/V staged once per 512 q
// (2x more amortized than r18's 1024-block config, which had a 2-round tail).
// 16 waves/CU (same as r18). VGPR/LDS unchanged -> no spill risk.
// Softmax without max-subtraction (scores small, f32-safe, identical result).
// K-pack rows: 0..76 text, 77..79 zero, 80..83 ip, 84..87 ips, 88..95 zero.
// attnout aliases qh (in-place): each wave reads exactly the q it overwrites.
__global__ __launch_bounds__(512)
void attn_kernel(const _Float16* __restrict__ qh,
                 const _Float16* __restrict__ ktxt, const _Float16* __restrict__ vT,
                 const _Float16* __restrict__ ipk, const _Float16* __restrict__ ipvT,
                 const _Float16* __restrict__ ipsk, const int* __restrict__ mask,
                 _Float16* __restrict__ attnout)
{
    __shared__ __align__(16) _Float16 sK[96 * ASTR];
    __shared__ __align__(16) _Float16 sVT[80 * ASTR];
    __shared__ __align__(16) _Float16 sP[128 * ASTR];

    const int q0 = blockIdx.x * 512;            // 512 q-rows per block
    const int bh = blockIdx.y;
    const int b = bh >> 3, h = bh & 7;
    const int tid = threadIdx.x;
    const float scale = 0.11180339887498948f;   // 1/sqrt(80)
    const half8 hz = {0, 0, 0, 0, 0, 0, 0, 0};

    for (int idx = tid; idx < 96 * 13; idx += 512) {
        int row = idx / 13, c8 = idx % 13;
        half8 v = hz;
        if (c8 < 10) {
            if (row < 77)                       v = *(const half8*)&ktxt[(size_t)(b * LTXT + row) * 640 + h * DH + c8 * 8];
            else if (row >= 80 && row < 84)     v = *(const half8*)&ipk [(size_t)(b * NTOK + row - 80) * 640 + h * DH + c8 * 8];
            else if (row >= 84 && row < 88)     v = *(const half8*)&ipsk[(size_t)(b * NTOK + row - 84) * 640 + h * DH + c8 * 8];
        }
        *(half8*)&sK[row * ASTR + c8 * 8] = v;
    }
    for (int idx = tid; idx < 80 * 13; idx += 512) {
        int row = idx / 13, c8 = idx % 13;
        size_t g = (size_t)b * 640 + h * DH + row;
        half8 v = hz;
        if (c8 < 10) {
            v = *(const half8*)&vT[g * 80 + c8 * 8];
        } else if (c8 == 10) {
            half4 ip = *(const half4*)&ipvT[g * 4];
            v[0] = ip[0]; v[1] = ip[1]; v[2] = ip[2]; v[3] = ip[3];
        }
        *(half8*)&sVT[row * ASTR + c8 * 8] = v;
    }
    __syncthreads();

    const int lane = tid & 63;
    const int w = tid >> 6;                     // 0..7
    const int rb = w * 16;                      // sP row base (0..112)
    const int lrow = lane & 15, lhi = lane >> 4;
    const bool t4ok = (64 + lrow) < 77;

    for (int it = 0; it < 4; ++it) {
        const int qrow = q0 + it * 128 + rb;    // this wave's global q base

        const _Float16* qbase = qh + (size_t)(b * SS + qrow + lrow) * 640 + h * DH + lhi * 8;
        half8 a0 = *(const half8*)(qbase);
        half8 a1 = *(const half8*)(qbase + 32);
        half8 a2 = (lhi < 2) ? *(const half8*)(qbase + 64) : hz;

        f32x4 acc[6];
        #pragma unroll
        for (int nt = 0; nt < 6; ++nt) acc[nt] = (f32x4){0.f, 0.f, 0.f, 0.f};

        #pragma unroll
        for (int nt = 0; nt < 6; ++nt) {
            const _Float16* kb = &sK[(nt * 16 + lrow) * ASTR + lhi * 8];
            acc[nt] = __builtin_amdgcn_mfma_f32_16x16x32_f16(a0, *(const half8*)(kb),      acc[nt], 0, 0, 0);
            acc[nt] = __builtin_amdgcn_mfma_f32_16x16x32_f16(a1, *(const half8*)(kb + 32), acc[nt], 0, 0, 0);
            acc[nt] = __builtin_amdgcn_mfma_f32_16x16x32_f16(a2, *(const half8*)(kb + 64), acc[nt], 0, 0, 0);
        }

        #pragma unroll
        for (int nt = 0; nt < 6; ++nt) acc[nt] = acc[nt] * scale;

        #pragma unroll
        for (int r = 0; r < 4; ++r) {
            float e0 = __expf(acc[0][r]), e1 = __expf(acc[1][r]);
            float e2 = __expf(acc[2][r]), e3 = __expf(acc[3][r]);
            float e4 = t4ok ? __expf(acc[4][r]) : 0.f;
            float sm = e0 + e1 + e2 + e3 + e4;
            sm += __shfl_xor(sm, 1); sm += __shfl_xor(sm, 2);
            sm += __shfl_xor(sm, 4); sm += __shfl_xor(sm, 8);
            float inv = 1.f / sm;
            acc[0][r] = e0 * inv; acc[1][r] = e1 * inv; acc[2][r] = e2 * inv;
            acc[3][r] = e3 * inv; acc[4][r] = e4 * inv;

            float e5 = __expf(acc[5][r]);
            float sm5 = e5 + __shfl_xor(e5, 1);
            sm5 += __shfl_xor(sm5, 2);
            float p5 = e5 / sm5;
            float po = __shfl_xor(p5, 4);
            int gq = qrow + lhi * 4 + r;
            float fac = (mask[gq] != 0) ? 0.01f : 1.0f;
            float pc = fmaxf(p5, po) * fac;
            acc[5][r] = (lrow < 4) ? pc : 0.f;
        }

        #pragma unroll
        for (int nt = 0; nt < 6; ++nt)
            #pragma unroll
            for (int r = 0; r < 4; ++r)
                sP[(rb + lhi * 4 + r) * ASTR + nt * 16 + lrow] = (_Float16)acc[nt][r];

        f32x4 o[5];
        #pragma unroll
        for (int nt = 0; nt < 5; ++nt) o[nt] = (f32x4){0.f, 0.f, 0.f, 0.f};
        {
            const _Float16* pbase = &sP[(rb + lrow) * ASTR + lhi * 8];
            half8 p0 = *(const half8*)(pbase);
            half8 p1 = *(const half8*)(pbase + 32);
            half8 p2 = *(const half8*)(pbase + 64);
            #pragma unroll
            for (int nt = 0; nt < 5; ++nt) {
                const _Float16* vb = &sVT[(nt * 16 + lrow) * ASTR + lhi * 8];
                o[nt] = __builtin_amdgcn_mfma_f32_16x16x32_f16(p0, *(const half8*)(vb),      o[nt], 0, 0, 0);
                o[nt] = __builtin_amdgcn_mfma_f32_16x16x32_f16(p1, *(const half8*)(vb + 32), o[nt], 0, 0, 0);
                o[nt] = __builtin_amdgcn_mfma_f32_16x16x32_f16(p2, *(const half8*)(vb + 64), o[nt], 0, 0, 0);
            }
        }

        #pragma unroll
        for (int nt = 0; nt < 5; ++nt)
            #pragma unroll
            for (int r = 0; r < 4; ++r)
                attnout[(size_t)(b * SS + qrow + lhi * 4 + r) * 640 + h * DH + nt * 16 + lrow] =
                    (_Float16)o[nt][r];
    }
}

// ---------------------------------------------------------------- launch
extern "C" void kernel_launch(void* const* d_in, const int* in_sizes, int n_in,
                              void* d_out, int out_size, void* d_ws, size_t ws_size,
                              hipStream_t stream) {
    const float* hidden = (const float*)d_in[0];
    const float* ehs    = (const float*)d_in[1];
    const int*   mask   = (const int*)d_in[2];
    const float* Wq     = (const float*)d_in[3];
    const float* Wk     = (const float*)d_in[4];
    const float* Wv     = (const float*)d_in[5];
    const float* Wkip   = (const float*)d_in[6];
    const float* Wvip   = (const float*)d_in[7];
    const float* Wksip  = (const float*)d_in[8];
    const float* Wo     = (const float*)d_in[9];
    const float* bo     = (const float*)d_in[10];

    // ws layout (total 87,255,040 B, proven footprint):
    //   region A @ 0: ehs16 (1,044,480) + 5 x WT (983,040 ea) = 5,959,680
    //     dead after proj_and_convert; qhA (first written by gemm0) overlays it.
    //   qhA    0           41,943,040   q -> attn out (in-place)
    //   hid16  41,943,040  41,943,040
    //   BqT    83,886,080     819,200
    //   BoT    84,705,280     819,200
    //   ktxt   85,524,480     788,480
    //   vT     86,312,960     819,200   [b*640+d][80]
    //   ipk    87,132,160      40,960
    //   ipvT   87,173,120      40,960   [b*640+d][4]
    //   ipsk   87,214,080      40,960   -> ends 87,255,040
    char* ws = (char*)d_ws;
    _Float16* qhA    = (_Float16*)(ws);
    _Float16* ehs16  = (_Float16*)(ws);                      // overlaid by qhA later
    _Float16* WkT    = (_Float16*)(ws + 1044480);
    _Float16* WvT    = (_Float16*)(ws + 2027520);
    _Float16* WkipT  = (_Float16*)(ws + 3010560);
    _Float16* WvipT  = (_Float16*)(ws + 3993600);
    _Float16* WksipT = (_Float16*)(ws + 4976640);            // region A ends 5,959,680
    _Float16* hid16  = (_Float16*)(ws + 41943040);
    _Float16* BqT    = (_Float16*)(ws + 83886080);
    _Float16* BoT    = (_Float16*)(ws + 84705280);
    _Float16* ktxt   = (_Float16*)(ws + 85524480);
    _Float16* vT     = (_Float16*)(ws + 86312960);
    _Float16* ipk    = (_Float16*)(ws + 87132160);
    _Float16* ipvT   = (_Float16*)(ws + 87173120);
    _Float16* ipsk   = (_Float16*)(ws + 87214080);

    mega_convert<<<1055, 256, 0, stream>>>(ehs, ehs16, Wq, BqT, Wo, BoT,
                                           Wk, Wv, Wkip, Wvip, Wksip,
                                           WkT, WvT, WkipT, WvipT, WksipT);
    proj_and_convert<<<10470, 256, 0, stream>>>(ehs16, WkT, WvT, WkipT, WvipT, WksipT,
                                                ktxt, vT, ipk, ipvT, ipsk,
                                                hidden, hid16);
    gemm_f16<0><<<1024, 256, 0, stream>>>(hid16, BqT, nullptr, nullptr, qhA);
    attn_kernel<<<dim3(8, 64), 512, 0, stream>>>(qhA, ktxt, vT, ipk, ipvT, ipsk, mask, qhA);
    gemm_f16<1><<<1024, 256, 0, stream>>>(qhA, BoT, bo, hid16, d_out);
}

// Round 21
// 132.975 us; speedup vs baseline: 1.2998x; 1.0112x over previous
//
#include <hip/hip_runtime.h>
#include <hip/hip_bf16.h>
#include <hip/hip_fp16.h>

#define BB 8
#define SS 4096
#define CC 640
#define CDIM 768
#define LTXT 77
#define NTOK 4
#define DH 80
#define ASTR 104   // padded LDS row stride (f16) for attention tiles

typedef __attribute__((ext_vector_type(8))) _Float16 half8;
typedef __attribute__((ext_vector_type(4))) _Float16 half4;
typedef __attribute__((ext_vector_type(4))) float f32x4;

__device__ inline void gload_lds16(const void* g, void* l) {
    __builtin_amdgcn_global_load_lds((__attribute__((address_space(1))) void*)g,
                                     (__attribute__((address_space(3))) void*)l, 16, 0, 0);
}

// ---------------------------------------------------------------- mega convert
// One launch for all small converts. Job ranges on blockIdx.x:
//   [0,255)      ehs f32 -> ehs16           (255 blocks, 65280 x8 elems)
//   [255,355)    Wq[640][640] -> BqT[n][k]  (10 x 10 tiles)
//   [355,455)    Wo[640][640] -> BoT[n][k]
//   [455,1055)   5 proj weights [768][640] -> WT[640][768] (5 x 120 tiles)
__global__ __launch_bounds__(256)
void mega_convert(const float* __restrict__ ehs, _Float16* __restrict__ ehs16,
                  const float* __restrict__ Wq, _Float16* __restrict__ BqT,
                  const float* __restrict__ Wo, _Float16* __restrict__ BoT,
                  const float* __restrict__ W0, const float* __restrict__ W1,
                  const float* __restrict__ W2, const float* __restrict__ W3,
                  const float* __restrict__ W4,
                  _Float16* __restrict__ T0, _Float16* __restrict__ T1,
                  _Float16* __restrict__ T2, _Float16* __restrict__ T3,
                  _Float16* __restrict__ T4)
{
    __shared__ float t[64][65];
    const int z = blockIdx.x;
    const int tid = threadIdx.x;

    if (z < 255) {                      // ehs convert (no LDS)
        int i = z * 256 + tid;
        const float4* p = (const float4*)(ehs + (size_t)i * 8);
        float4 a = p[0], b = p[1];
        half8 h = {(_Float16)a.x, (_Float16)a.y, (_Float16)a.z, (_Float16)a.w,
                   (_Float16)b.x, (_Float16)b.y, (_Float16)b.z, (_Float16)b.w};
        *(half8*)(ehs16 + (size_t)i * 8) = h;
        return;
    }

    const float* W; _Float16* T; int n0, k0, Kdim;
    if (z < 455) {                      // 640x640 transposes
        int j = z - 255;
        W = (j < 100) ? Wq : Wo;
        T = (j < 100) ? BqT : BoT;
        j %= 100;
        n0 = (j / 10) * 64; k0 = (j % 10) * 64; Kdim = 640;
    } else {                            // 768x640 proj-weight transposes
        int j = z - 455;
        int wsel = j / 120, rem = j % 120;
        W = (wsel == 0) ? W0 : (wsel == 1) ? W1 : (wsel == 2) ? W2 : (wsel == 3) ? W3 : W4;
        T = (wsel == 0) ? T0 : (wsel == 1) ? T1 : (wsel == 2) ? T2 : (wsel == 3) ? T3 : T4;
        n0 = (rem % 10) * 64; k0 = (rem / 10) * 64; Kdim = CDIM;
    }
    for (int idx = tid; idx < 64 * 64; idx += 256) {
        int kk = idx >> 6, nn = idx & 63;
        t[kk][nn] = W[(size_t)(k0 + kk) * 640 + n0 + nn];
    }
    __syncthreads();
    for (int idx = tid; idx < 64 * 64; idx += 256) {
        int nn = idx >> 6, kk = idx & 63;
        T[(size_t)(n0 + nn) * Kdim + k0 + kk] = (_Float16)t[kk][nn];
    }
}

// ---------------------------------------------------------------- proj GEMM + hidden convert (fused launch)
// Blocks [0,230): projection MFMA GEMM. Blocks [230,10470): hidden f32->f16.
__global__ __launch_bounds__(256)
void proj_and_convert(const _Float16* __restrict__ A16,
                      const _Float16* __restrict__ WT0, const _Float16* __restrict__ WT1,
                      const _Float16* __restrict__ WT2, const _Float16* __restrict__ WT3,
                      const _Float16* __restrict__ WT4,
                      _Float16* __restrict__ O0, _Float16* __restrict__ O1,
                      _Float16* __restrict__ O2, _Float16* __restrict__ O3,
                      _Float16* __restrict__ O4,
                      const float* __restrict__ hidden, _Float16* __restrict__ hid16)
{
    __shared__ __align__(16) _Float16 sA[64 * 64];
    __shared__ __align__(16) _Float16 sB[64 * 64];
    const int tid = threadIdx.x;

    if (blockIdx.x >= 230) {            // hidden convert branch
        int i = (blockIdx.x - 230) * 256 + tid;
        if (i < 2621440) {
            const float4* p = (const float4*)(hidden + (size_t)i * 8);
            float4 a = p[0], b = p[1];
            half8 h = {(_Float16)a.x, (_Float16)a.y, (_Float16)a.z, (_Float16)a.w,
                       (_Float16)b.x, (_Float16)b.y, (_Float16)b.z, (_Float16)b.w};
            *(half8*)(hid16 + (size_t)i * 8) = h;
        }
        return;
    }

    const int job = blockIdx.x;
    int wsel, mtile, ntile;
    if (job < 200) { wsel = job / 100; mtile = (job % 100) / 10; ntile = job % 10; }
    else { int j = job - 200; wsel = 2 + j / 10; mtile = 0; ntile = j % 10; }
    const _Float16* WT = (wsel == 0) ? WT0 : (wsel == 1) ? WT1 : (wsel == 2) ? WT2 : (wsel == 3) ? WT3 : WT4;
    const int Mv = (wsel < 2) ? 616 : 32;
    const int bm = mtile * 64, bn = ntile * 64;

    const _Float16* asrc[2];
    const _Float16* bsrc[2];
    int sslot[2];
    #pragma unroll
    for (int p = 0; p < 2; ++p) {
        int s = p * 256 + tid;
        int row = s >> 3, sub = s & 7;
        int c = sub ^ (row & 7);
        int m = bm + row; if (m > Mv - 1) m = Mv - 1;
        int srcrow;
        if (wsel < 2) srcrow = (m / 77) * 85 + (m % 77);
        else { int b2 = m >> 2, t2 = m & 3; srcrow = b2 * 85 + ((wsel == 4) ? 81 : 77) + t2; }
        asrc[p] = A16 + (size_t)srcrow * CDIM + c * 8;
        bsrc[p] = WT + (size_t)(bn + row) * CDIM + c * 8;
        sslot[p] = s * 8;
    }

    const int lane = tid & 63, w = tid >> 6;
    const int wm = w >> 1, wn = w & 1;
    const int lrow = lane & 15, lhi = lane >> 4;

    f32x4 acc[2][2];
    #pragma unroll
    for (int mt = 0; mt < 2; ++mt)
        #pragma unroll
        for (int nt = 0; nt < 2; ++nt)
            acc[mt][nt] = (f32x4){0.f, 0.f, 0.f, 0.f};

    for (int k0 = 0; k0 < CDIM; k0 += 64) {
        #pragma unroll
        for (int p = 0; p < 2; ++p) {
            gload_lds16(asrc[p] + k0, sA + sslot[p]);
            gload_lds16(bsrc[p] + k0, sB + sslot[p]);
        }
        __syncthreads();
        #pragma unroll
        for (int ks = 0; ks < 2; ++ks) {
            half8 af[2], bf[2];
            #pragma unroll
            for (int mt = 0; mt < 2; ++mt) {
                int row = wm * 32 + mt * 16 + lrow;
                int sub = (ks * 4 + lhi) ^ (row & 7);
                af[mt] = *(const half8*)&sA[row * 64 + sub * 8];
            }
            #pragma unroll
            for (int nt = 0; nt < 2; ++nt) {
                int row = wn * 32 + nt * 16 + lrow;
                int sub = (ks * 4 + lhi) ^ (row & 7);
                bf[nt] = *(const half8*)&sB[row * 64 + sub * 8];
            }
            #pragma unroll
            for (int mt = 0; mt < 2; ++mt)
                #pragma unroll
                for (int nt = 0; nt < 2; ++nt)
                    acc[mt][nt] = __builtin_amdgcn_mfma_f32_16x16x32_f16(af[mt], bf[nt], acc[mt][nt], 0, 0, 0);
        }
        __syncthreads();
    }

    _Float16* Op = (wsel == 0) ? O0 : (wsel == 2) ? O2 : O4;
    #pragma unroll
    for (int mt = 0; mt < 2; ++mt) {
        #pragma unroll
        for (int nt = 0; nt < 2; ++nt) {
            int col = bn + wn * 32 + nt * 16 + lrow;
            #pragma unroll
            for (int r = 0; r < 4; ++r) {
                int m = bm + wm * 32 + mt * 16 + lhi * 4 + r;
                if (m < Mv) {
                    _Float16 val = (_Float16)acc[mt][nt][r];
                    if (wsel == 1) {
                        int bb = m / 77, j = m % 77;
                        O1[((size_t)bb * 640 + col) * 80 + j] = val;
                    } else if (wsel == 3) {
                        int bb = m >> 2, t = m & 3;
                        O3[((size_t)bb * 640 + col) * 4 + t] = val;
                    } else {
                        Op[(size_t)m * 640 + col] = val;
                    }
                }
            }
        }
    }
}

// ---------------------------------------------------------------- f16 MFMA GEMM (2-phase dbuf, 128x160 tile)
// C[M,640] = A[M,640] @ BT[640,640]^T. Tile 128x160 (N = 4 x 160):
// 40 MFMA / 18.4 KB staged per K-tile; grid 1024 = exactly 2 residency rounds;
// LDS 73.7 KB (2 blocks/CU). Round 19: -12 us vs 128x128.
// Schedule: stage tile t+1 FIRST, compute t, ONE barrier per tile (round 14).
// XCD-bijective swizzle (1024 = 8 x 128), n-inner (4 n-tiles per A panel).
// EPI 0: f16 store. EPI 1: 0.5*(acc+bias)+resid16, f32 store (resid is f16).
template<int EPI>
__global__ __launch_bounds__(256)
void gemm_f16(const _Float16* __restrict__ A, const _Float16* __restrict__ BT,
              const float* __restrict__ bias, const _Float16* __restrict__ resid,
              void* __restrict__ Cp)
{
    __shared__ __align__(16) _Float16 sA[2][128 * 64];
    __shared__ __align__(16) _Float16 sB[2][160 * 64];

    const int tid = threadIdx.x;
    const int lane = tid & 63;
    const int w = tid >> 6, wm = w >> 1, wn = w & 1;
    const int lrow = lane & 15, lhi = lane >> 4;

    const int orig = blockIdx.x;
    const int wgid = (orig & 7) * 128 + (orig >> 3);
    const int bm = (wgid >> 2) * 128, bn = (wgid & 3) * 160;

    const _Float16* asrc[4];
    int aslot[4];
    #pragma unroll
    for (int p = 0; p < 4; ++p) {
        int s = p * 256 + tid;
        int row = s >> 3, sub = s & 7;
        int c = sub ^ (row & 7);                // inverse-swizzled source
        asrc[p] = A + (size_t)(bm + row) * 640 + c * 8;
        aslot[p] = s * 8;
    }
    const _Float16* bsrc[5];
    int bslot[5];
    #pragma unroll
    for (int p = 0; p < 5; ++p) {
        int s = p * 256 + tid;
        int row = s >> 3, sub = s & 7;
        int c = sub ^ (row & 7);
        bsrc[p] = BT + (size_t)(bn + row) * 640 + c * 8;
        bslot[p] = s * 8;
    }

    f32x4 acc[4][5];
    #pragma unroll
    for (int mt = 0; mt < 4; ++mt)
        #pragma unroll
        for (int nt = 0; nt < 5; ++nt)
            acc[mt][nt] = (f32x4){0.f, 0.f, 0.f, 0.f};

    #pragma unroll
    for (int p = 0; p < 4; ++p) gload_lds16(asrc[p], &sA[0][aslot[p]]);
    #pragma unroll
    for (int p = 0; p < 5; ++p) gload_lds16(bsrc[p], &sB[0][bslot[p]]);
    __syncthreads();

    for (int t = 0; t < 10; ++t) {
        const int cur = t & 1;
        if (t < 9) {
            const int k1 = (t + 1) * 64;
            #pragma unroll
            for (int p = 0; p < 4; ++p) gload_lds16(asrc[p] + k1, &sA[cur ^ 1][aslot[p]]);
            #pragma unroll
            for (int p = 0; p < 5; ++p) gload_lds16(bsrc[p] + k1, &sB[cur ^ 1][bslot[p]]);
        }
        __builtin_amdgcn_s_setprio(1);
        #pragma unroll
        for (int ks = 0; ks < 2; ++ks) {
            half8 af[4], bf[5];
            #pragma unroll
            for (int mt = 0; mt < 4; ++mt) {
                int row = wm * 64 + mt * 16 + lrow;
                int sub = (ks * 4 + lhi) ^ (row & 7);
                af[mt] = *(const half8*)&sA[cur][row * 64 + sub * 8];
            }
            #pragma unroll
            for (int nt = 0; nt < 5; ++nt) {
                int row = wn * 80 + nt * 16 + lrow;
                int sub = (ks * 4 + lhi) ^ (row & 7);
                bf[nt] = *(const half8*)&sB[cur][row * 64 + sub * 8];
            }
            #pragma unroll
            for (int mt = 0; mt < 4; ++mt)
                #pragma unroll
                for (int nt = 0; nt < 5; ++nt)
                    acc[mt][nt] = __builtin_amdgcn_mfma_f32_16x16x32_f16(af[mt], bf[nt], acc[mt][nt], 0, 0, 0);
        }
        __builtin_amdgcn_s_setprio(0);
        __syncthreads();
    }

    #pragma unroll
    for (int mt = 0; mt < 4; ++mt) {
        #pragma unroll
        for (int nt = 0; nt < 5; ++nt) {
            int row0 = bm + wm * 64 + mt * 16 + lhi * 4;
            int col = bn + wn * 80 + nt * 16 + lrow;
            #pragma unroll
            for (int r = 0; r < 4; ++r) {
                float v = acc[mt][nt][r];
                if (EPI == 0) {
                    ((_Float16*)Cp)[(size_t)(row0 + r) * 640 + col] = (_Float16)v;
                } else {
                    float o = 0.5f * (v + bias[col]) + (float)resid[(size_t)(row0 + r) * 640 + col];
                    ((float*)Cp)[(size_t)(row0 + r) * 640 + col] = o;
                }
            }
        }
    }
}

// ---------------------------------------------------------------- MFMA attention (8 waves, V from L2)
// r20 structure (8 waves x 4 iters x 128 rows, 512 blocks = 1 residency round)
// with the sVT staging DIET: PV B-frags for j in [0,64) read DIRECTLY from
// global vT (819 KB, L2-resident, j contiguous in memory) — staging data that
// caches fit was pure overhead. Only the j in [64,96) tail (text 64..79,
// ip 80..83, zeros) stays in LDS: sV2[80][40] = 6.4 KB.
// LDS 63.2 -> 53.0 KB => 3 blocks/CU x 8 waves = 24 waves/CU (was 16) on a
// ~70%-stall latency-bound kernel. Per-wave code otherwise identical.
// Softmax without max-subtraction (scores small, f32-safe, identical result).
// K-pack rows: 0..76 text, 77..79 zero, 80..83 ip, 84..87 ips, 88..95 zero.
// attnout aliases qh (in-place): each wave reads exactly the q it overwrites.
__global__ __launch_bounds__(512)
void attn_kernel(const _Float16* __restrict__ qh,
                 const _Float16* __restrict__ ktxt, const _Float16* __restrict__ vT,
                 const _Float16* __restrict__ ipk, const _Float16* __restrict__ ipvT,
                 const _Float16* __restrict__ ipsk, const int* __restrict__ mask,
                 _Float16* __restrict__ attnout)
{
    __shared__ __align__(16) _Float16 sK[96 * ASTR];
    __shared__ __align__(16) _Float16 sV2[80 * 40];   // [d][j-64], j in [64,96)
    __shared__ __align__(16) _Float16 sP[128 * ASTR];

    const int q0 = blockIdx.x * 512;            // 512 q-rows per block
    const int bh = blockIdx.y;
    const int b = bh >> 3, h = bh & 7;
    const int tid = threadIdx.x;
    const float scale = 0.11180339887498948f;   // 1/sqrt(80)
    const half8 hz = {0, 0, 0, 0, 0, 0, 0, 0};

    for (int idx = tid; idx < 96 * 13; idx += 512) {
        int row = idx / 13, c8 = idx % 13;
        half8 v = hz;
        if (c8 < 10) {
            if (row < 77)                       v = *(const half8*)&ktxt[(size_t)(b * LTXT + row) * 640 + h * DH + c8 * 8];
            else if (row >= 80 && row < 84)     v = *(const half8*)&ipk [(size_t)(b * NTOK + row - 80) * 640 + h * DH + c8 * 8];
            else if (row >= 84 && row < 88)     v = *(const half8*)&ipsk[(size_t)(b * NTOK + row - 84) * 640 + h * DH + c8 * 8];
        }
        *(half8*)&sK[row * ASTR + c8 * 8] = v;
    }
    // V tail: sV2[d][c8*8] <- j = 64 + c8*8 (c8 0..1: text V; 2: ip + zeros; 3: zeros)
    for (int idx = tid; idx < 80 * 4; idx += 512) {
        int row = idx >> 2, c8 = idx & 3;
        size_t g = (size_t)b * 640 + h * DH + row;
        half8 v = hz;
        if (c8 < 2) {
            v = *(const half8*)&vT[g * 80 + 64 + c8 * 8];
        } else if (c8 == 2) {
            half4 ip = *(const half4*)&ipvT[g * 4];
            v[0] = ip[0]; v[1] = ip[1]; v[2] = ip[2]; v[3] = ip[3];
        }
        *(half8*)&sV2[row * 40 + c8 * 8] = v;
    }
    __syncthreads();

    const int lane = tid & 63;
    const int w = tid >> 6;                     // 0..7
    const int rb = w * 16;                      // sP row base (0..112)
    const int lrow = lane & 15, lhi = lane >> 4;
    const bool t4ok = (64 + lrow) < 77;
    // uniform V base for this (b,h); per-nt row = nt*16+lrow, j chunk = lhi*8
    const _Float16* vg = vT + ((size_t)b * 640 + h * DH) * 80;

    for (int it = 0; it < 4; ++it) {
        const int qrow = q0 + it * 128 + rb;    // this wave's global q base

        const _Float16* qbase = qh + (size_t)(b * SS + qrow + lrow) * 640 + h * DH + lhi * 8;
        half8 a0 = *(const half8*)(qbase);
        half8 a1 = *(const half8*)(qbase + 32);
        half8 a2 = (lhi < 2) ? *(const half8*)(qbase + 64) : hz;

        f32x4 acc[6];
        #pragma unroll
        for (int nt = 0; nt < 6; ++nt) acc[nt] = (f32x4){0.f, 0.f, 0.f, 0.f};

        #pragma unroll
        for (int nt = 0; nt < 6; ++nt) {
            const _Float16* kb = &sK[(nt * 16 + lrow) * ASTR + lhi * 8];
            acc[nt] = __builtin_amdgcn_mfma_f32_16x16x32_f16(a0, *(const half8*)(kb),      acc[nt], 0, 0, 0);
            acc[nt] = __builtin_amdgcn_mfma_f32_16x16x32_f16(a1, *(const half8*)(kb + 32), acc[nt], 0, 0, 0);
            acc[nt] = __builtin_amdgcn_mfma_f32_16x16x32_f16(a2, *(const half8*)(kb + 64), acc[nt], 0, 0, 0);
        }

        #pragma unroll
        for (int nt = 0; nt < 6; ++nt) acc[nt] = acc[nt] * scale;

        #pragma unroll
        for (int r = 0; r < 4; ++r) {
            float e0 = __expf(acc[0][r]), e1 = __expf(acc[1][r]);
            float e2 = __expf(acc[2][r]), e3 = __expf(acc[3][r]);
            float e4 = t4ok ? __expf(acc[4][r]) : 0.f;
            float sm = e0 + e1 + e2 + e3 + e4;
            sm += __shfl_xor(sm, 1); sm += __shfl_xor(sm, 2);
            sm += __shfl_xor(sm, 4); sm += __shfl_xor(sm, 8);
            float inv = 1.f / sm;
            acc[0][r] = e0 * inv; acc[1][r] = e1 * inv; acc[2][r] = e2 * inv;
            acc[3][r] = e3 * inv; acc[4][r] = e4 * inv;

            float e5 = __expf(acc[5][r]);
            float sm5 = e5 + __shfl_xor(e5, 1);
            sm5 += __shfl_xor(sm5, 2);
            float p5 = e5 / sm5;
            float po = __shfl_xor(p5, 4);
            int gq = qrow + lhi * 4 + r;
            float fac = (mask[gq] != 0) ? 0.01f : 1.0f;
            float pc = fmaxf(p5, po) * fac;
            acc[5][r] = (lrow < 4) ? pc : 0.f;
        }

        #pragma unroll
        for (int nt = 0; nt < 6; ++nt)
            #pragma unroll
            for (int r = 0; r < 4; ++r)
                sP[(rb + lhi * 4 + r) * ASTR + nt * 16 + lrow] = (_Float16)acc[nt][r];

        f32x4 o[5];
        #pragma unroll
        for (int nt = 0; nt < 5; ++nt) o[nt] = (f32x4){0.f, 0.f, 0.f, 0.f};
        {
            const _Float16* pbase = &sP[(rb + lrow) * ASTR + lhi * 8];
            half8 p0 = *(const half8*)(pbase);
            half8 p1 = *(const half8*)(pbase + 32);
            half8 p2 = *(const half8*)(pbase + 64);
            #pragma unroll
            for (int nt = 0; nt < 5; ++nt) {
                const _Float16* vrow = vg + (size_t)(nt * 16 + lrow) * 80 + lhi * 8;
                half8 vb0 = *(const half8*)(vrow);          // j = lhi*8      (L2)
                half8 vb1 = *(const half8*)(vrow + 32);     // j = lhi*8 + 32 (L2)
                half8 vb2 = *(const half8*)&sV2[(nt * 16 + lrow) * 40 + lhi * 8]; // j+64 tail
                o[nt] = __builtin_amdgcn_mfma_f32_16x16x32_f16(p0, vb0, o[nt], 0, 0, 0);
                o[nt] = __builtin_amdgcn_mfma_f32_16x16x32_f16(p1, vb1, o[nt], 0, 0, 0);
                o[nt] = __builtin_amdgcn_mfma_f32_16x16x32_f16(p2, vb2, o[nt], 0, 0, 0);
            }
        }

        #pragma unroll
        for (int nt = 0; nt < 5; ++nt)
            #pragma unroll
            for (int r = 0; r < 4; ++r)
                attnout[(size_t)(b * SS + qrow + lhi * 4 + r) * 640 + h * DH + nt * 16 + lrow] =
                    (_Float16)o[nt][r];
    }
}

// ---------------------------------------------------------------- launch
extern "C" void kernel_launch(void* const* d_in, const int* in_sizes, int n_in,
                              void* d_out, int out_size, void* d_ws, size_t ws_size,
                              hipStream_t stream) {
    const float* hidden = (const float*)d_in[0];
    const float* ehs    = (const float*)d_in[1];
    const int*   mask   = (const int*)d_in[2];
    const float* Wq     = (const float*)d_in[3];
    const float* Wk     = (const float*)d_in[4];
    const float* Wv     = (const float*)d_in[5];
    const float* Wkip   = (const float*)d_in[6];
    const float* Wvip   = (const float*)d_in[7];
    const float* Wksip  = (const float*)d_in[8];
    const float* Wo     = (const float*)d_in[9];
    const float* bo     = (const float*)d_in[10];

    // ws layout (total 87,255,040 B, proven footprint):
    //   region A @ 0: ehs16 (1,044,480) + 5 x WT (983,040 ea) = 5,959,680
    //     dead after proj_and_convert; qhA (first written by gemm0) overlays it.
    //   qhA    0           41,943,040   q -> attn out (in-place)
    //   hid16  41,943,040  41,943,040
    //   BqT    83,886,080     819,200
    //   BoT    84,705,280     819,200
    //   ktxt   85,524,480     788,480
    //   vT     86,312,960     819,200   [b*640+d][80]
    //   ipk    87,132,160      40,960
    //   ipvT   87,173,120      40,960   [b*640+d][4]
    //   ipsk   87,214,080      40,960   -> ends 87,255,040
    char* ws = (char*)d_ws;
    _Float16* qhA    = (_Float16*)(ws);
    _Float16* ehs16  = (_Float16*)(ws);                      // overlaid by qhA later
    _Float16* WkT    = (_Float16*)(ws + 1044480);
    _Float16* WvT    = (_Float16*)(ws + 2027520);
    _Float16* WkipT  = (_Float16*)(ws + 3010560);
    _Float16* WvipT  = (_Float16*)(ws + 3993600);
    _Float16* WksipT = (_Float16*)(ws + 4976640);            // region A ends 5,959,680
    _Float16* hid16  = (_Float16*)(ws + 41943040);
    _Float16* BqT    = (_Float16*)(ws + 83886080);
    _Float16* BoT    = (_Float16*)(ws + 84705280);
    _Float16* ktxt   = (_Float16*)(ws + 85524480);
    _Float16* vT     = (_Float16*)(ws + 86312960);
    _Float16* ipk    = (_Float16*)(ws + 87132160);
    _Float16* ipvT   = (_Float16*)(ws + 87173120);
    _Float16* ipsk   = (_Float16*)(ws + 87214080);

    mega_convert<<<1055, 256, 0, stream>>>(ehs, ehs16, Wq, BqT, Wo, BoT,
                                           Wk, Wv, Wkip, Wvip, Wksip,
                                           WkT, WvT, WkipT, WvipT, WksipT);
    proj_and_convert<<<10470, 256, 0, stream>>>(ehs16, WkT, WvT, WkipT, WvipT, WksipT,
                                                ktxt, vT, ipk, ipvT, ipsk,
                                                hidden, hid16);
    gemm_f16<0><<<1024, 256, 0, stream>>>(hid16, BqT, nullptr, nullptr, qhA);
    attn_kernel<<<dim3(8, 64), 512, 0, stream>>>(qhA, ktxt, vT, ipk, ipvT, ipsk, mask, qhA);
    gemm_f16<1><<<1024, 256, 0, stream>>>(qhA, BoT, bo, hid16, d_out);
}